// Round 7
// baseline (6135.781 us; speedup 1.0000x reference)
//
#include <hip/hip_runtime.h>

// Round 7: round 5 (verified PASS) with ONE change: no cross-head accP register
// accumulator (it spilled to scratch -> 3.6GB phantom traffic). Instead each
// head's proj partial is RMW'd into d_out fp32 immediately (h==0 initializes
// with proj_b). Zero d_ws usage. Everything else byte-identical to round 5.

typedef __attribute__((ext_vector_type(8))) short bf16x8;
typedef __attribute__((ext_vector_type(4))) float f32x4;

#define OFF_Q 0          // Q [176][64] bf16 stride 128B (swizzled); later act[n][64]
#define OFF_K 22528      // K [176][64] stride 128B
#define OFF_V 45056      // Vt [64][192] stride 384B (transposed V)
#define OFF_A 69632      // agent_v^T [64][192] stride 384B
#define OFF_P 94208      // P [176][192] stride 384B; qkv_w staging (192x80B) and W staging (256x128B) overlay
#define SMEM_BYTES 161792

__device__ __forceinline__ unsigned short f2bf(float f) {
  unsigned int u = __float_as_uint(f);
  u += 0x7FFFu + ((u >> 16) & 1u);
  return (unsigned short)(u >> 16);
}
__device__ __forceinline__ float bf2f(unsigned short v) {
  return __uint_as_float(((unsigned int)v) << 16);
}
__device__ __forceinline__ f32x4 mfma16(bf16x8 a, bf16x8 b, f32x4 c) {
  return __builtin_amdgcn_mfma_f32_16x16x32_bf16(a, b, c, 0, 0, 0);
}
__device__ __forceinline__ bf16x8 cvt8(float4 a, float4 b) {
  bf16x8 v;
  v[0] = (short)f2bf(a.x); v[1] = (short)f2bf(a.y);
  v[2] = (short)f2bf(a.z); v[3] = (short)f2bf(a.w);
  v[4] = (short)f2bf(b.x); v[5] = (short)f2bf(b.y);
  v[6] = (short)f2bf(b.z); v[7] = (short)f2bf(b.w);
  return v;
}
// swizzled LDS helpers: addr = base + row*stride + (colbyte ^ ((row&7)<<4))
__device__ __forceinline__ bf16x8 ld8s(const char* sm, int base, int stride, int row, int colbyte) {
  return *(const bf16x8*)(sm + base + row * stride + (colbyte ^ ((row & 7) << 4)));
}
__device__ __forceinline__ void st2s(char* sm, int base, int stride, int row, int col, unsigned short v) {
  *(unsigned short*)(sm + base + row * stride + ((col * 2) ^ ((row & 7) << 4))) = v;
}
__device__ __forceinline__ float ld2s(const char* sm, int base, int stride, int row, int col) {
  return bf2f(*(const unsigned short*)(sm + base + row * stride + ((col * 2) ^ ((row & 7) << 4))));
}

__global__ __launch_bounds__(384, 1) void attn_kernel(
    const float* __restrict__ x, const float* __restrict__ qkv_w,
    const float* __restrict__ proj_w, const float* __restrict__ proj_b,
    const float* __restrict__ dwc_w, const float* __restrict__ dwc_b,
    const float* __restrict__ an, const float* __restrict__ ah,
    const float* __restrict__ aw, const float* __restrict__ na,
    const float* __restrict__ ha, const float* __restrict__ wa,
    float* __restrict__ out)
{
  __shared__ __align__(16) char sm[SMEM_BYTES];
  const int b = blockIdx.x;
  const int tid = threadIdx.x;
  const int wave = tid >> 6;
  const int lane = tid & 63;
  const int l15 = lane & 15;
  const int l4 = lane >> 4;
  const int mt0 = wave * 2;
  const int mt1 = wave * 2 + 1;   // ==11 for wave 5 -> skipped
  const float* xb = x + (size_t)b * 169 * 256;

  // zero all LDS once (logical pad cols of V/A must be zero)
  {
    int* p = (int*)sm;
    for (int i = tid; i < SMEM_BYTES / 4; i += 384) p[i] = 0;
  }

  const f32x4 z = {0.f, 0.f, 0.f, 0.f};

  for (int h = 0; h < 4; ++h) {
    __syncthreads();   // protect region reuse across heads (and after LDS zero)

    // ---- Phase 1: QKV MFMA: [176 x 192(3*64)] = x[b] @ w_head^T ----
    {
      f32x4 acc0[12], acc1[12];
#pragma unroll
      for (int i = 0; i < 12; ++i) { acc0[i] = z; acc1[i] = z; }

      const int arow0 = mt0 * 16 + l15;
      const int arow1 = mt1 * 16 + l15;
      const int gr0 = arow0 < 169 ? arow0 : 168;
      const int gr1 = arow1 < 169 ? arow1 : 168;

      for (int ks = 0; ks < 8; ++ks) {
        {   // stage qkv_w slice [192 rows][32 k] fp32->bf16, linear stride 80B
          const int row = tid >> 1;
          const int half = tid & 1;
          const int grow = ((row >> 6) << 8) + h * 64 + (row & 63);
          const float* src = qkv_w + grow * 256 + ks * 32 + half * 16;
          float4 f0 = *(const float4*)(src);
          float4 f1 = *(const float4*)(src + 4);
          float4 f2 = *(const float4*)(src + 8);
          float4 f3 = *(const float4*)(src + 12);
          char* dst = sm + OFF_P + row * 80 + half * 32;
          *(bf16x8*)(dst) = cvt8(f0, f1);
          *(bf16x8*)(dst + 16) = cvt8(f2, f3);
        }
        __syncthreads();
        bf16x8 af0, af1;
        {
          const float* p0 = xb + gr0 * 256 + ks * 32 + l4 * 8;
          af0 = cvt8(*(const float4*)p0, *(const float4*)(p0 + 4));
        }
        {
          const float* p1 = xb + gr1 * 256 + ks * 32 + l4 * 8;
          af1 = cvt8(*(const float4*)p1, *(const float4*)(p1 + 4));
        }
#pragma unroll
        for (int nt = 0; nt < 12; ++nt) {
          bf16x8 bw = *(const bf16x8*)(sm + OFF_P + (nt * 16 + l15) * 80 + l4 * 16);
          acc0[nt] = mfma16(af0, bw, acc0[nt]);
          if (mt1 < 11) acc1[nt] = mfma16(af1, bw, acc1[nt]);
        }
        __syncthreads();
      }
      // write Q,K row-major [n][d] (stride 128, swizzled); V transposed [d][n] (stride 384)
#pragma unroll
      for (int nt = 0; nt < 12; ++nt) {
        const int mat = nt >> 2;
        const int d = (nt & 3) * 16 + l15;
#pragma unroll
        for (int r = 0; r < 4; ++r) {
          {
            const int n = mt0 * 16 + l4 * 4 + r;
            const unsigned short u = f2bf(acc0[nt][r]);
            if (mat == 0)      st2s(sm, OFF_Q, 128, n, d, u);
            else if (mat == 1) st2s(sm, OFF_K, 128, n, d, u);
            else               st2s(sm, OFF_V, 384, d, n, u);
          }
          if (mt1 < 11) {
            const int n = mt1 * 16 + l4 * 4 + r;
            const unsigned short u = f2bf(acc1[nt][r]);
            if (mat == 0)      st2s(sm, OFF_Q, 128, n, d, u);
            else if (mat == 1) st2s(sm, OFF_K, 128, n, d, u);
            else               st2s(sm, OFF_V, 384, d, n, u);
          }
        }
      }
    }
    __syncthreads();

    // ---- S-phase (shared): S = 0.125*Q@B^T + bias, row softmax -> P ----
    auto sphase = [&](int srcBase, int which) {
#pragma unroll
      for (int mi = 0; mi < 2; ++mi) {
        const int mt = wave * 2 + mi;
        if (mt >= 11) continue;
        const int arow = mt * 16 + l15;
        bf16x8 a0 = ld8s(sm, OFF_Q, 128, arow, l4 * 16);
        bf16x8 a1 = ld8s(sm, OFF_Q, 128, arow, 64 + l4 * 16);
        f32x4 s[11];
#pragma unroll
        for (int nt = 0; nt < 11; ++nt) {
          const int brow = nt * 16 + l15;
          bf16x8 b0 = ld8s(sm, srcBase, 128, brow, l4 * 16);
          bf16x8 b1 = ld8s(sm, srcBase, 128, brow, 64 + l4 * 16);
          f32x4 c = z;
          c = mfma16(a0, b0, c);
          c = mfma16(a1, b1, c);
          s[nt] = c;
        }
        const int rbase = mt * 16 + l4 * 4;
#pragma unroll
        for (int nt = 0; nt < 11; ++nt) {
          const int cc = nt * 16 + l15;
          const int ccl = cc > 168 ? 168 : cc;
          const int yc = (ccl * 79) >> 10;   // ccl/13
          const int xc = ccl - yc * 13;
#pragma unroll
          for (int r = 0; r < 4; ++r) {
            const int rr = rbase + r;
            const int rrl = rr > 168 ? 168 : rr;
            float bias;
            if (which == 0) {
              bias = an[h * 28561 + rrl * 169 + ccl]
                   + ah[(h * 169 + rrl) * 13 + yc]
                   + aw[(h * 169 + rrl) * 13 + xc];
            } else {
              const int yn = (rrl * 79) >> 10;
              const int xn = rrl - yn * 13;
              bias = na[h * 28561 + ccl * 169 + rrl]
                   + ha[(h * 13 + yn) * 169 + ccl]
                   + wa[(h * 13 + xn) * 169 + ccl];
            }
            const float v = s[nt][r] * 0.125f + bias;
            s[nt][r] = (cc > 168) ? -1e30f : v;
          }
        }
#pragma unroll
        for (int r = 0; r < 4; ++r) {
          float m = s[0][r];
#pragma unroll
          for (int nt = 1; nt < 11; ++nt) m = fmaxf(m, s[nt][r]);
          m = fmaxf(m, __shfl_xor(m, 1));
          m = fmaxf(m, __shfl_xor(m, 2));
          m = fmaxf(m, __shfl_xor(m, 4));
          m = fmaxf(m, __shfl_xor(m, 8));
          float sum = 0.f;
#pragma unroll
          for (int nt = 0; nt < 11; ++nt) { const float e = __expf(s[nt][r] - m); s[nt][r] = e; sum += e; }
          sum += __shfl_xor(sum, 1);
          sum += __shfl_xor(sum, 2);
          sum += __shfl_xor(sum, 4);
          sum += __shfl_xor(sum, 8);
          const float inv = 1.f / sum;
#pragma unroll
          for (int nt = 0; nt < 11; ++nt) s[nt][r] *= inv;
        }
#pragma unroll
        for (int nt = 0; nt < 11; ++nt)
#pragma unroll
          for (int r = 0; r < 4; ++r)
            st2s(sm, OFF_P, 384, rbase + r, nt * 16 + l15, f2bf(s[nt][r]));
#pragma unroll
        for (int r = 0; r < 4; ++r)     // zero logical pad cols 176..191
          st2s(sm, OFF_P, 384, rbase + r, 176 + l15, 0);
      }
    };

    sphase(OFF_K, 0);        // S1: agent attention
    __syncthreads();

    // ---- P1V: agent_v = P1 @ V -> store transposed into OFF_A ----
#pragma unroll
    for (int mi = 0; mi < 2; ++mi) {
      const int mt = wave * 2 + mi;
      if (mt >= 11) continue;
      const int arow = mt * 16 + l15;
      f32x4 o[4];
#pragma unroll
      for (int i = 0; i < 4; ++i) o[i] = z;
#pragma unroll
      for (int ks = 0; ks < 6; ++ks) {
        bf16x8 a = ld8s(sm, OFF_P, 384, arow, ks * 64 + l4 * 16);
#pragma unroll
        for (int nt = 0; nt < 4; ++nt) {
          bf16x8 bv = ld8s(sm, OFF_V, 384, nt * 16 + l15, ks * 64 + l4 * 16);
          o[nt] = mfma16(a, bv, o[nt]);
        }
      }
#pragma unroll
      for (int nt = 0; nt < 4; ++nt)
#pragma unroll
        for (int r = 0; r < 4; ++r)
          st2s(sm, OFF_A, 384, nt * 16 + l15, mt * 16 + l4 * 4 + r, f2bf(o[nt][r]));
    }
    __syncthreads();

    sphase(OFF_Q, 1);        // S2: q attention (B operand = Q itself)
    __syncthreads();

    // ---- P2A + dwconv -> act[n][64] into OFF_Q region (Q dead after S2) ----
#pragma unroll
    for (int mi = 0; mi < 2; ++mi) {
      const int mt = wave * 2 + mi;
      if (mt >= 11) continue;
      const int arow = mt * 16 + l15;
      f32x4 o[4];
#pragma unroll
      for (int i = 0; i < 4; ++i) o[i] = z;
#pragma unroll
      for (int ks = 0; ks < 6; ++ks) {
        bf16x8 a = ld8s(sm, OFF_P, 384, arow, ks * 64 + l4 * 16);
#pragma unroll
        for (int nt = 0; nt < 4; ++nt) {
          bf16x8 bv = ld8s(sm, OFF_A, 384, nt * 16 + l15, ks * 64 + l4 * 16);
          o[nt] = mfma16(a, bv, o[nt]);
        }
      }
#pragma unroll
      for (int nt = 0; nt < 4; ++nt) {
        const int d = nt * 16 + l15;
        const int c = h * 64 + d;
        const float bc = dwc_b[c];
#pragma unroll
        for (int r = 0; r < 4; ++r) {
          const int n = mt * 16 + l4 * 4 + r;
          const int nl = n > 168 ? 168 : n;
          const int y = (nl * 79) >> 10;
          const int xx = nl - y * 13;
          float dw = bc;
#pragma unroll
          for (int ky = 0; ky < 3; ++ky) {
            const int yy = y + ky - 1;
            if ((unsigned)yy >= 13u) continue;
#pragma unroll
            for (int kx = 0; kx < 3; ++kx) {
              const int x2 = xx + kx - 1;
              if ((unsigned)x2 >= 13u) continue;
              dw += dwc_w[c * 9 + ky * 3 + kx] * ld2s(sm, OFF_V, 384, d, yy * 13 + x2);
            }
          }
          st2s(sm, OFF_Q, 128, n, d, f2bf(o[nt][r] + dw));   // act
        }
      }
    }
    __syncthreads();

    // ---- stage Wt[j][64] = proj_w[j][h*64+d] into OFF_P (P dead), stride 128B ----
    for (int idx = tid; idx < 2048; idx += 384) {
      const int j = idx >> 3;          // 0..255
      const int c8 = idx & 7;          // 8-elem chunk of d
      const float* src = proj_w + j * 256 + h * 64 + c8 * 8;
      float4 f0 = *(const float4*)(src);
      float4 f1 = *(const float4*)(src + 4);
      *(bf16x8*)(sm + OFF_P + j * 128 + ((c8 * 16) ^ ((j & 7) << 4))) = cvt8(f0, f1);
    }
    __syncthreads();

    // ---- proj partial MFMA: out (+)= act @ Wt^T  (K=64), immediate fp32 RMW ----
#pragma unroll
    for (int mi = 0; mi < 2; ++mi) {
      const int mt = wave * 2 + mi;
      if (mt >= 11) continue;
      const int arow = mt * 16 + l15;
      bf16x8 af0 = ld8s(sm, OFF_Q, 128, arow, l4 * 16);
      bf16x8 af1 = ld8s(sm, OFF_Q, 128, arow, 64 + l4 * 16);
#pragma unroll
      for (int nt = 0; nt < 16; ++nt) {
        const int brow = nt * 16 + l15;
        bf16x8 bf0 = ld8s(sm, OFF_P, 128, brow, l4 * 16);
        bf16x8 bf1 = ld8s(sm, OFF_P, 128, brow, 64 + l4 * 16);
        f32x4 c = z;
        c = mfma16(af0, bf0, c);
        c = mfma16(af1, bf1, c);
        const int col = nt * 16 + l15;
#pragma unroll
        for (int r = 0; r < 4; ++r) {
          const int n = mt * 16 + l4 * 4 + r;
          if (n < 169) {
            float* p = out + ((size_t)b * 169 + n) * 256 + col;
            if (h == 0) *p = c[r] + proj_b[col];
            else        *p += c[r];
          }
        }
      }
    }
    // next head's loop-start barrier protects W/act regions
  }
}

extern "C" void kernel_launch(void* const* d_in, const int* in_sizes, int n_in,
                              void* d_out, int out_size, void* d_ws, size_t ws_size,
                              hipStream_t stream) {
  const float* x      = (const float*)d_in[0];
  const float* qkv_w  = (const float*)d_in[1];
  const float* proj_w = (const float*)d_in[2];
  const float* proj_b = (const float*)d_in[3];
  const float* dwc_w  = (const float*)d_in[4];
  const float* dwc_b  = (const float*)d_in[5];
  const float* an     = (const float*)d_in[6];
  const float* na     = (const float*)d_in[7];
  const float* ah     = (const float*)d_in[8];
  const float* aw     = (const float*)d_in[9];
  const float* ha     = (const float*)d_in[10];
  const float* wa     = (const float*)d_in[11];

  attn_kernel<<<1024, 384, 0, stream>>>(
      x, qkv_w, proj_w, proj_b, dwc_w, dwc_b,
      an, ah, aw, na, ha, wa, (float*)d_out);
}

// Round 8
// 5649.157 us; speedup vs baseline: 1.0861x; 1.0861x over previous
//
#include <hip/hip_runtime.h>

// Round 8: round 7 + (1) two-pass softmax with running max + deferred
// normalization (kills the s[11] register block -> no scratch spill),
// (2) persistent blocks: grid=256, each handles 4 b's (tables stay L2-hot),
// (3) nontemporal final-head out stores. Wave structure identical to round 7.

typedef __attribute__((ext_vector_type(8))) short bf16x8;
typedef __attribute__((ext_vector_type(4))) float f32x4;

#define OFF_Q 0          // Q [176][64] bf16 stride 128B (swizzled); later act[n][64]
#define OFF_K 22528      // K [176][64] stride 128B
#define OFF_V 45056      // Vt [64][192] stride 384B (transposed V)
#define OFF_A 69632      // agent_v^T [64][192] stride 384B
#define OFF_P 94208      // P [176][192] stride 384B; qkv_w staging (192x80B) and W staging (256x128B) overlay
#define SMEM_BYTES 161792

__device__ __forceinline__ unsigned short f2bf(float f) {
  unsigned int u = __float_as_uint(f);
  u += 0x7FFFu + ((u >> 16) & 1u);
  return (unsigned short)(u >> 16);
}
__device__ __forceinline__ float bf2f(unsigned short v) {
  return __uint_as_float(((unsigned int)v) << 16);
}
__device__ __forceinline__ f32x4 mfma16(bf16x8 a, bf16x8 b, f32x4 c) {
  return __builtin_amdgcn_mfma_f32_16x16x32_bf16(a, b, c, 0, 0, 0);
}
__device__ __forceinline__ bf16x8 cvt8(float4 a, float4 b) {
  bf16x8 v;
  v[0] = (short)f2bf(a.x); v[1] = (short)f2bf(a.y);
  v[2] = (short)f2bf(a.z); v[3] = (short)f2bf(a.w);
  v[4] = (short)f2bf(b.x); v[5] = (short)f2bf(b.y);
  v[6] = (short)f2bf(b.z); v[7] = (short)f2bf(b.w);
  return v;
}
// swizzled LDS helpers: addr = base + row*stride + (colbyte ^ ((row&7)<<4))
__device__ __forceinline__ bf16x8 ld8s(const char* sm, int base, int stride, int row, int colbyte) {
  return *(const bf16x8*)(sm + base + row * stride + (colbyte ^ ((row & 7) << 4)));
}
__device__ __forceinline__ void st2s(char* sm, int base, int stride, int row, int col, unsigned short v) {
  *(unsigned short*)(sm + base + row * stride + ((col * 2) ^ ((row & 7) << 4))) = v;
}
__device__ __forceinline__ float ld2s(const char* sm, int base, int stride, int row, int col) {
  return bf2f(*(const unsigned short*)(sm + base + row * stride + ((col * 2) ^ ((row & 7) << 4))));
}

__global__ __launch_bounds__(384, 1) void attn_kernel(
    const float* __restrict__ x, const float* __restrict__ qkv_w,
    const float* __restrict__ proj_w, const float* __restrict__ proj_b,
    const float* __restrict__ dwc_w, const float* __restrict__ dwc_b,
    const float* __restrict__ an, const float* __restrict__ ah,
    const float* __restrict__ aw, const float* __restrict__ na,
    const float* __restrict__ ha, const float* __restrict__ wa,
    float* __restrict__ out)
{
  __shared__ __align__(16) char sm[SMEM_BYTES];
  const int tid = threadIdx.x;
  const int wave = tid >> 6;
  const int lane = tid & 63;
  const int l15 = lane & 15;
  const int l4 = lane >> 4;
  const int mt0 = wave * 2;
  const int mt1 = wave * 2 + 1;   // ==11 for wave 5 -> skipped
  const f32x4 z = {0.f, 0.f, 0.f, 0.f};

  // zero all LDS once per block
  {
    int* p = (int*)sm;
    for (int i = tid; i < SMEM_BYTES / 4; i += 384) p[i] = 0;
  }

  for (int bi = 0; bi < 4; ++bi) {
    const int b = blockIdx.x + 256 * bi;
    const float* xb = x + (size_t)b * 169 * 256;

    for (int h = 0; h < 4; ++h) {
      __syncthreads();   // previous iteration fully consumed (and initial zero)

      // ---- Phase 1: QKV MFMA: [176 x 192(3*64)] = x[b] @ w_head^T ----
      {
        f32x4 acc0[12], acc1[12];
#pragma unroll
        for (int i = 0; i < 12; ++i) { acc0[i] = z; acc1[i] = z; }

        const int arow0 = mt0 * 16 + l15;
        const int arow1 = mt1 * 16 + l15;
        const int gr0 = arow0 < 169 ? arow0 : 168;
        const int gr1 = arow1 < 169 ? arow1 : 168;

        for (int ks = 0; ks < 8; ++ks) {
          {   // stage qkv_w slice [192 rows][32 k] fp32->bf16, linear stride 80B
            const int row = tid >> 1;
            const int half = tid & 1;
            const int grow = ((row >> 6) << 8) + h * 64 + (row & 63);
            const float* src = qkv_w + grow * 256 + ks * 32 + half * 16;
            float4 f0 = *(const float4*)(src);
            float4 f1 = *(const float4*)(src + 4);
            float4 f2 = *(const float4*)(src + 8);
            float4 f3 = *(const float4*)(src + 12);
            char* dst = sm + OFF_P + row * 80 + half * 32;
            *(bf16x8*)(dst) = cvt8(f0, f1);
            *(bf16x8*)(dst + 16) = cvt8(f2, f3);
          }
          __syncthreads();
          bf16x8 af0, af1;
          {
            const float* p0 = xb + gr0 * 256 + ks * 32 + l4 * 8;
            af0 = cvt8(*(const float4*)p0, *(const float4*)(p0 + 4));
          }
          {
            const float* p1 = xb + gr1 * 256 + ks * 32 + l4 * 8;
            af1 = cvt8(*(const float4*)p1, *(const float4*)(p1 + 4));
          }
#pragma unroll
          for (int nt = 0; nt < 12; ++nt) {
            bf16x8 bw = *(const bf16x8*)(sm + OFF_P + (nt * 16 + l15) * 80 + l4 * 16);
            acc0[nt] = mfma16(af0, bw, acc0[nt]);
            if (mt1 < 11) acc1[nt] = mfma16(af1, bw, acc1[nt]);
          }
          __syncthreads();
        }
        // write Q,K row-major [n][d] (stride 128, swizzled); V transposed [d][n] (stride 384)
#pragma unroll
        for (int nt = 0; nt < 12; ++nt) {
          const int mat = nt >> 2;
          const int d = (nt & 3) * 16 + l15;
#pragma unroll
          for (int r = 0; r < 4; ++r) {
            {
              const int n = mt0 * 16 + l4 * 4 + r;
              const unsigned short u = f2bf(acc0[nt][r]);
              if (mat == 0)      st2s(sm, OFF_Q, 128, n, d, u);
              else if (mat == 1) st2s(sm, OFF_K, 128, n, d, u);
              else               st2s(sm, OFF_V, 384, d, n, u);
            }
            if (mt1 < 11) {
              const int n = mt1 * 16 + l4 * 4 + r;
              const unsigned short u = f2bf(acc1[nt][r]);
              if (mat == 0)      st2s(sm, OFF_Q, 128, n, d, u);
              else if (mat == 1) st2s(sm, OFF_K, 128, n, d, u);
              else               st2s(sm, OFF_V, 384, d, n, u);
            }
          }
        }
      }
      __syncthreads();

      // ---- S-phase: two-pass, running max, deferred normalization ----
      // Pass A: per nt compute S tile + bias, track max, store bf16 S to P.
      // Pass B: read back, exp, sum, store unnormalized e. inv returned in regs.
      float inv1[2][4], inv2[2][4];
      auto sphase = [&](int srcBase, int which, float (&inv)[2][4]) {
#pragma unroll
        for (int mi = 0; mi < 2; ++mi) {
          const int mt = wave * 2 + mi;
          if (mt >= 11) continue;
          const int arow = mt * 16 + l15;
          const int rbase = mt * 16 + l4 * 4;
          bf16x8 a0 = ld8s(sm, OFF_Q, 128, arow, l4 * 16);
          bf16x8 a1 = ld8s(sm, OFF_Q, 128, arow, 64 + l4 * 16);
          float m[4] = {-3.0e38f, -3.0e38f, -3.0e38f, -3.0e38f};
#pragma unroll
          for (int nt = 0; nt < 11; ++nt) {
            const int brow = nt * 16 + l15;
            bf16x8 b0 = ld8s(sm, srcBase, 128, brow, l4 * 16);
            bf16x8 b1 = ld8s(sm, srcBase, 128, brow, 64 + l4 * 16);
            f32x4 c = z;
            c = mfma16(a0, b0, c);
            c = mfma16(a1, b1, c);
            const int cc = nt * 16 + l15;
            const int ccl = cc > 168 ? 168 : cc;
            const int yc = (ccl * 79) >> 10;   // ccl/13
            const int xc = ccl - yc * 13;
#pragma unroll
            for (int r = 0; r < 4; ++r) {
              const int rr = rbase + r;
              const int rrl = rr > 168 ? 168 : rr;
              float bias;
              if (which == 0) {
                bias = an[h * 28561 + rrl * 169 + ccl]
                     + ah[(h * 169 + rrl) * 13 + yc]
                     + aw[(h * 169 + rrl) * 13 + xc];
              } else {
                const int yn = (rrl * 79) >> 10;
                const int xn = rrl - yn * 13;
                bias = na[h * 28561 + ccl * 169 + rrl]
                     + ha[(h * 13 + yn) * 169 + ccl]
                     + wa[(h * 13 + xn) * 169 + ccl];
              }
              float v = c[r] * 0.125f + bias;
              v = (cc > 168) ? -3.0e38f : v;
              m[r] = fmaxf(m[r], v);
              st2s(sm, OFF_P, 384, rr, cc, f2bf(v));
            }
          }
#pragma unroll
          for (int r = 0; r < 4; ++r) {
            m[r] = fmaxf(m[r], __shfl_xor(m[r], 1));
            m[r] = fmaxf(m[r], __shfl_xor(m[r], 2));
            m[r] = fmaxf(m[r], __shfl_xor(m[r], 4));
            m[r] = fmaxf(m[r], __shfl_xor(m[r], 8));
          }
          float sum[4] = {0.f, 0.f, 0.f, 0.f};
#pragma unroll
          for (int nt = 0; nt < 11; ++nt) {
            const int cc = nt * 16 + l15;
#pragma unroll
            for (int r = 0; r < 4; ++r) {
              const float s = ld2s(sm, OFF_P, 384, rbase + r, cc);
              const float e = __expf(s - m[r]);
              sum[r] += e;
              st2s(sm, OFF_P, 384, rbase + r, cc, f2bf(e));
            }
          }
#pragma unroll
          for (int r = 0; r < 4; ++r) {     // zero logical pad cols 176..191
            st2s(sm, OFF_P, 384, rbase + r, 176 + l15, 0);
            sum[r] += __shfl_xor(sum[r], 1);
            sum[r] += __shfl_xor(sum[r], 2);
            sum[r] += __shfl_xor(sum[r], 4);
            sum[r] += __shfl_xor(sum[r], 8);
            inv[mi][r] = 1.f / sum[r];
          }
        }
      };

      sphase(OFF_K, 0, inv1);        // S1: agent attention (unnormalized e in P)
      __syncthreads();

      // ---- P1V: agent_v = (P1 @ V) * inv1 -> store transposed into OFF_A ----
#pragma unroll
      for (int mi = 0; mi < 2; ++mi) {
        const int mt = wave * 2 + mi;
        if (mt >= 11) continue;
        const int arow = mt * 16 + l15;
        f32x4 o[4];
#pragma unroll
        for (int i = 0; i < 4; ++i) o[i] = z;
#pragma unroll
        for (int ks = 0; ks < 6; ++ks) {
          bf16x8 a = ld8s(sm, OFF_P, 384, arow, ks * 64 + l4 * 16);
#pragma unroll
          for (int nt = 0; nt < 4; ++nt) {
            bf16x8 bv = ld8s(sm, OFF_V, 384, nt * 16 + l15, ks * 64 + l4 * 16);
            o[nt] = mfma16(a, bv, o[nt]);
          }
        }
#pragma unroll
        for (int nt = 0; nt < 4; ++nt)
#pragma unroll
          for (int r = 0; r < 4; ++r)
            st2s(sm, OFF_A, 384, nt * 16 + l15, mt * 16 + l4 * 4 + r,
                 f2bf(o[nt][r] * inv1[mi][r]));
      }
      __syncthreads();

      sphase(OFF_Q, 1, inv2);        // S2: q attention (B operand = Q itself)
      __syncthreads();

      // ---- P2A + dwconv -> act[n][64] into OFF_Q region (Q dead after S2) ----
#pragma unroll
      for (int mi = 0; mi < 2; ++mi) {
        const int mt = wave * 2 + mi;
        if (mt >= 11) continue;
        const int arow = mt * 16 + l15;
        f32x4 o[4];
#pragma unroll
        for (int i = 0; i < 4; ++i) o[i] = z;
#pragma unroll
        for (int ks = 0; ks < 6; ++ks) {
          bf16x8 a = ld8s(sm, OFF_P, 384, arow, ks * 64 + l4 * 16);
#pragma unroll
          for (int nt = 0; nt < 4; ++nt) {
            bf16x8 bv = ld8s(sm, OFF_A, 384, nt * 16 + l15, ks * 64 + l4 * 16);
            o[nt] = mfma16(a, bv, o[nt]);
          }
        }
#pragma unroll
        for (int nt = 0; nt < 4; ++nt) {
          const int d = nt * 16 + l15;
          const int c = h * 64 + d;
          const float bc = dwc_b[c];
#pragma unroll
          for (int r = 0; r < 4; ++r) {
            const int n = mt * 16 + l4 * 4 + r;
            const int nl = n > 168 ? 168 : n;
            const int y = (nl * 79) >> 10;
            const int xx = nl - y * 13;
            float dw = bc;
#pragma unroll
            for (int ky = 0; ky < 3; ++ky) {
              const int yy = y + ky - 1;
              if ((unsigned)yy >= 13u) continue;
#pragma unroll
              for (int kx = 0; kx < 3; ++kx) {
                const int x2 = xx + kx - 1;
                if ((unsigned)x2 >= 13u) continue;
                dw += dwc_w[c * 9 + ky * 3 + kx] * ld2s(sm, OFF_V, 384, d, yy * 13 + x2);
              }
            }
            st2s(sm, OFF_Q, 128, n, d, f2bf(o[nt][r] * inv2[mi][r] + dw));   // act
          }
        }
      }
      __syncthreads();

      // ---- stage Wt[j][64] = proj_w[j][h*64+d] into OFF_P (P dead), stride 128B ----
      for (int idx = tid; idx < 2048; idx += 384) {
        const int j = idx >> 3;          // 0..255
        const int c8 = idx & 7;          // 8-elem chunk of d
        const float* src = proj_w + j * 256 + h * 64 + c8 * 8;
        float4 f0 = *(const float4*)(src);
        float4 f1 = *(const float4*)(src + 4);
        *(bf16x8*)(sm + OFF_P + j * 128 + ((c8 * 16) ^ ((j & 7) << 4))) = cvt8(f0, f1);
      }
      __syncthreads();

      // ---- proj partial MFMA: out (+)= act @ Wt^T  (K=64), fp32 RMW ----
#pragma unroll
      for (int mi = 0; mi < 2; ++mi) {
        const int mt = wave * 2 + mi;
        if (mt >= 11) continue;
        const int arow = mt * 16 + l15;
        bf16x8 af0 = ld8s(sm, OFF_Q, 128, arow, l4 * 16);
        bf16x8 af1 = ld8s(sm, OFF_Q, 128, arow, 64 + l4 * 16);
#pragma unroll
        for (int nt = 0; nt < 16; ++nt) {
          const int brow = nt * 16 + l15;
          bf16x8 bf0 = ld8s(sm, OFF_P, 128, brow, l4 * 16);
          bf16x8 bf1 = ld8s(sm, OFF_P, 128, brow, 64 + l4 * 16);
          f32x4 c = z;
          c = mfma16(af0, bf0, c);
          c = mfma16(af1, bf1, c);
          const int col = nt * 16 + l15;
#pragma unroll
          for (int r = 0; r < 4; ++r) {
            const int n = mt * 16 + l4 * 4 + r;
            if (n < 169) {
              float* p = out + ((size_t)b * 169 + n) * 256 + col;
              if (h == 0)      *p = c[r] + proj_b[col];
              else if (h == 3) __builtin_nontemporal_store(*p + c[r], p);
              else             *p += c[r];
            }
          }
        }
      }
      // next iteration's loop-start barrier protects W/act regions
    }
  }
}

extern "C" void kernel_launch(void* const* d_in, const int* in_sizes, int n_in,
                              void* d_out, int out_size, void* d_ws, size_t ws_size,
                              hipStream_t stream) {
  const float* x      = (const float*)d_in[0];
  const float* qkv_w  = (const float*)d_in[1];
  const float* proj_w = (const float*)d_in[2];
  const float* proj_b = (const float*)d_in[3];
  const float* dwc_w  = (const float*)d_in[4];
  const float* dwc_b  = (const float*)d_in[5];
  const float* an     = (const float*)d_in[6];
  const float* na     = (const float*)d_in[7];
  const float* ah     = (const float*)d_in[8];
  const float* aw     = (const float*)d_in[9];
  const float* ha     = (const float*)d_in[10];
  const float* wa     = (const float*)d_in[11];

  attn_kernel<<<256, 384, 0, stream>>>(
      x, qkv_w, proj_w, proj_b, dwc_w, dwc_b,
      an, ah, aw, na, ha, wa, (float*)d_out);
}

// Round 10
// 4033.245 us; speedup vs baseline: 1.5213x; 1.4006x over previous
//
#include <hip/hip_runtime.h>

// Round 10: round 9 + the one fix: restore one-time LDS zero-init.
// (Round 9's NaN: never-written pad cols 176..191 of Vt/avT contain boot
// garbage; 0 x Inf/NaN-pattern = NaN in PV MFMA. Zeroing once per block is
// sufficient: those bytes are only ever re-written with finite bf16 data.)
// Everything else identical to round 9: 77.5KB LDS -> 2 blocks/CU, fused S+PV
// with in-register softmax + per-wave P_tmp, direct-global QKV fragments,
// 6 barriers per (b,h), per-head proj RMW epilogue. Zero d_ws.

typedef __attribute__((ext_vector_type(8))) short bf16x8;
typedef __attribute__((ext_vector_type(4))) float f32x4;

#define OFF_Q 0          // Q [176][64] bf16 stride 128 swizzled; Wproj[256][64] overlays 0..32768
#define OFF_K 22528      // K [176][64] stride 128 swizzled; avT [64][192] stride 384 overlays (24576B)
#define OFF_V 47104      // Vt [64][192] stride 384 swizzled; act [176][64] stride 128 overlays
#define OFF_T 71680      // P_tmp: per wave 1280B = [16][40] bf16 stride 80 (no swizzle)
#define SMEM_BYTES 79360

__device__ __forceinline__ unsigned short f2bf(float f) {
  unsigned int u = __float_as_uint(f);
  u += 0x7FFFu + ((u >> 16) & 1u);
  return (unsigned short)(u >> 16);
}
__device__ __forceinline__ float bf2f(unsigned short v) {
  return __uint_as_float(((unsigned int)v) << 16);
}
__device__ __forceinline__ f32x4 mfma16(bf16x8 a, bf16x8 b, f32x4 c) {
  return __builtin_amdgcn_mfma_f32_16x16x32_bf16(a, b, c, 0, 0, 0);
}
__device__ __forceinline__ bf16x8 cvt8(float4 a, float4 b) {
  bf16x8 v;
  v[0] = (short)f2bf(a.x); v[1] = (short)f2bf(a.y);
  v[2] = (short)f2bf(a.z); v[3] = (short)f2bf(a.w);
  v[4] = (short)f2bf(b.x); v[5] = (short)f2bf(b.y);
  v[6] = (short)f2bf(b.z); v[7] = (short)f2bf(b.w);
  return v;
}
__device__ __forceinline__ bf16x8 ld8s(const char* sm, int base, int stride, int row, int colbyte) {
  return *(const bf16x8*)(sm + base + row * stride + (colbyte ^ ((row & 7) << 4)));
}
__device__ __forceinline__ void st2s(char* sm, int base, int stride, int row, int col, unsigned short v) {
  *(unsigned short*)(sm + base + row * stride + ((col * 2) ^ ((row & 7) << 4))) = v;
}
__device__ __forceinline__ float ld2s(const char* sm, int base, int stride, int row, int col) {
  return bf2f(*(const unsigned short*)(sm + base + row * stride + ((col * 2) ^ ((row & 7) << 4))));
}

__global__ __launch_bounds__(384, 3) void attn_kernel(
    const float* __restrict__ x, const float* __restrict__ qkv_w,
    const float* __restrict__ proj_w, const float* __restrict__ proj_b,
    const float* __restrict__ dwc_w, const float* __restrict__ dwc_b,
    const float* __restrict__ an, const float* __restrict__ ah,
    const float* __restrict__ aw, const float* __restrict__ na,
    const float* __restrict__ ha, const float* __restrict__ wa,
    float* __restrict__ out)
{
  __shared__ __align__(16) char sm[SMEM_BYTES];
  const int b = blockIdx.x;
  const int tid = threadIdx.x;
  const int wave = tid >> 6;
  const int lane = tid & 63;
  const int l15 = lane & 15;
  const int l4 = lane >> 4;
  const int mt0 = wave * 2;
  const int mt1 = wave * 2 + 1;   // ==11 for wave 5 -> skipped
  const float* xb = x + (size_t)b * 169 * 256;
  const f32x4 z = {0.f, 0.f, 0.f, 0.f};

  // one-time LDS zero: pad bytes must never decode to Inf/NaN (0 x NaN = NaN)
  {
    int* p = (int*)sm;
    for (int i = tid; i < SMEM_BYTES / 4; i += 384) p[i] = 0;
  }

  // fused S-phase (in-reg softmax) + PV via per-wave P_tmp.
  auto fused = [&](int sBase, int pvBase, int which, int h, f32x4 (&o_all)[2][4]) {
#pragma unroll
    for (int mi = 0; mi < 2; ++mi) {
#pragma unroll
      for (int dt = 0; dt < 4; ++dt) o_all[mi][dt] = z;
      const int mt = wave * 2 + mi;
      if (mt >= 11) continue;
      const int arow = mt * 16 + l15;
      const int rbase = mt * 16 + l4 * 4;
      bf16x8 a0 = ld8s(sm, OFF_Q, 128, arow, l4 * 16);
      bf16x8 a1 = ld8s(sm, OFF_Q, 128, arow, 64 + l4 * 16);
      f32x4 s[11];
#pragma unroll
      for (int nt = 0; nt < 11; ++nt) {
        const int brow = nt * 16 + l15;
        bf16x8 b0 = ld8s(sm, sBase, 128, brow, l4 * 16);
        bf16x8 b1 = ld8s(sm, sBase, 128, brow, 64 + l4 * 16);
        f32x4 c = z;
        c = mfma16(a0, b0, c);
        c = mfma16(a1, b1, c);
        s[nt] = c;
      }
      // bias + mask
#pragma unroll
      for (int nt = 0; nt < 11; ++nt) {
        const int cc = nt * 16 + l15;
        const int ccl = cc > 168 ? 168 : cc;
        const int yc = (ccl * 79) >> 10;
        const int xc = ccl - yc * 13;
#pragma unroll
        for (int r = 0; r < 4; ++r) {
          const int rr = rbase + r;
          const int rrl = rr > 168 ? 168 : rr;
          float bias;
          if (which == 0) {
            bias = an[h * 28561 + rrl * 169 + ccl]
                 + ah[(h * 169 + rrl) * 13 + yc]
                 + aw[(h * 169 + rrl) * 13 + xc];
          } else {
            const int yn = (rrl * 79) >> 10;
            const int xn = rrl - yn * 13;
            bias = na[h * 28561 + ccl * 169 + rrl]
                 + ha[(h * 13 + yn) * 169 + ccl]
                 + wa[(h * 13 + xn) * 169 + ccl];
          }
          const float v = s[nt][r] * 0.125f + bias;
          s[nt][r] = (cc > 168) ? -3.0e38f : v;
        }
      }
      // in-register softmax
#pragma unroll
      for (int r = 0; r < 4; ++r) {
        float m = s[0][r];
#pragma unroll
        for (int nt = 1; nt < 11; ++nt) m = fmaxf(m, s[nt][r]);
        m = fmaxf(m, __shfl_xor(m, 1));
        m = fmaxf(m, __shfl_xor(m, 2));
        m = fmaxf(m, __shfl_xor(m, 4));
        m = fmaxf(m, __shfl_xor(m, 8));
        float sum = 0.f;
#pragma unroll
        for (int nt = 0; nt < 11; ++nt) { const float e = __expf(s[nt][r] - m); s[nt][r] = e; sum += e; }
        sum += __shfl_xor(sum, 1);
        sum += __shfl_xor(sum, 2);
        sum += __shfl_xor(sum, 4);
        sum += __shfl_xor(sum, 8);
        const float inv = 1.f / sum;
#pragma unroll
        for (int nt = 0; nt < 11; ++nt) s[nt][r] *= inv;
      }
      // PV: per 32-wide chunk pair, round-trip through per-wave P_tmp
      const int tb = OFF_T + wave * 1280;
#pragma unroll
      for (int np = 0; np < 6; ++np) {
        const int nt1 = 2 * np + 1;
#pragma unroll
        for (int r = 0; r < 4; ++r) {
          char* prow = sm + tb + (l4 * 4 + r) * 80;
          *(unsigned short*)(prow + l15 * 2) = f2bf(s[2 * np][r]);
          *(unsigned short*)(prow + 32 + l15 * 2) =
              (nt1 < 11) ? f2bf(s[nt1][r]) : (unsigned short)0;
        }
        bf16x8 af = *(const bf16x8*)(sm + tb + l15 * 80 + l4 * 16);
#pragma unroll
        for (int dt = 0; dt < 4; ++dt) {
          bf16x8 bv = ld8s(sm, pvBase, 384, dt * 16 + l15, np * 64 + l4 * 16);
          o_all[mi][dt] = mfma16(af, bv, o_all[mi][dt]);
        }
      }
    }
  };

  for (int h = 0; h < 4; ++h) {
    __syncthreads();   // previous head fully consumed (and initial zero done)

    // ---- QKV: [176 x 192] = x[b] @ w_head^T, direct-global frags, 0 barriers ----
    {
      f32x4 acc0[12], acc1[12];
#pragma unroll
      for (int i = 0; i < 12; ++i) { acc0[i] = z; acc1[i] = z; }
      const int arow0 = mt0 * 16 + l15;
      const int arow1 = mt1 * 16 + l15;
      const int gr0 = arow0 < 169 ? arow0 : 168;
      const int gr1 = arow1 < 169 ? arow1 : 168;

      for (int ks = 0; ks < 8; ++ks) {
        bf16x8 af0, af1;
        {
          const float* p0 = xb + gr0 * 256 + ks * 32 + l4 * 8;
          af0 = cvt8(*(const float4*)p0, *(const float4*)(p0 + 4));
        }
        {
          const float* p1 = xb + gr1 * 256 + ks * 32 + l4 * 8;
          af1 = cvt8(*(const float4*)p1, *(const float4*)(p1 + 4));
        }
#pragma unroll
        for (int nt = 0; nt < 12; ++nt) {
          const int wrow = nt * 16 + l15;
          const int grow = ((wrow >> 6) << 8) + h * 64 + (wrow & 63);
          const float* wp = qkv_w + grow * 256 + ks * 32 + l4 * 8;
          bf16x8 bw = cvt8(*(const float4*)wp, *(const float4*)(wp + 4));
          acc0[nt] = mfma16(af0, bw, acc0[nt]);
          if (mt1 < 11) acc1[nt] = mfma16(af1, bw, acc1[nt]);
        }
      }
      // write Q,K row-major [n][d] (stride 128, swz); V transposed [d][n] (stride 384, swz)
#pragma unroll
      for (int nt = 0; nt < 12; ++nt) {
        const int mat = nt >> 2;
        const int d = (nt & 3) * 16 + l15;
#pragma unroll
        for (int r = 0; r < 4; ++r) {
          {
            const int n = mt0 * 16 + l4 * 4 + r;
            const unsigned short u = f2bf(acc0[nt][r]);
            if (mat == 0)      st2s(sm, OFF_Q, 128, n, d, u);
            else if (mat == 1) st2s(sm, OFF_K, 128, n, d, u);
            else               st2s(sm, OFF_V, 384, d, n, u);
          }
          if (mt1 < 11) {
            const int n = mt1 * 16 + l4 * 4 + r;
            const unsigned short u = f2bf(acc1[nt][r]);
            if (mat == 0)      st2s(sm, OFF_Q, 128, n, d, u);
            else if (mat == 1) st2s(sm, OFF_K, 128, n, d, u);
            else               st2s(sm, OFF_V, 384, d, n, u);
          }
        }
      }
    }
    __syncthreads();

    // ---- S1 + P1V fused (B=K, PV-B=Vt) -> agent_v rows in regs ----
    f32x4 o1[2][4];
    fused(OFF_K, OFF_V, 0, h, o1);
    __syncthreads();                 // all S1 reads of K done
    // write avT [d][a] over K region
#pragma unroll
    for (int mi = 0; mi < 2; ++mi) {
      const int mt = wave * 2 + mi;
      if (mt >= 11) continue;
#pragma unroll
      for (int dt = 0; dt < 4; ++dt)
#pragma unroll
        for (int r = 0; r < 4; ++r)
          st2s(sm, OFF_K, 384, dt * 16 + l15, mt * 16 + l4 * 4 + r, f2bf(o1[mi][dt][r]));
    }
    __syncthreads();

    // ---- S2 + P2A fused (B=Q, PV-B=avT) + dwconv epilogue (reads Vt) ----
    f32x4 o2[2][4];
    fused(OFF_Q, OFF_K, 1, h, o2);
#pragma unroll
    for (int mi = 0; mi < 2; ++mi) {
      const int mt = wave * 2 + mi;
      if (mt >= 11) continue;
#pragma unroll
      for (int dt = 0; dt < 4; ++dt) {
        const int d = dt * 16 + l15;
        const int c = h * 64 + d;
        const float bc = dwc_b[c];
#pragma unroll
        for (int r = 0; r < 4; ++r) {
          const int n = mt * 16 + l4 * 4 + r;
          const int nl = n > 168 ? 168 : n;
          const int y = (nl * 79) >> 10;
          const int xx = nl - y * 13;
          float dw = bc;
#pragma unroll
          for (int ky = 0; ky < 3; ++ky) {
            const int yy = y + ky - 1;
            if ((unsigned)yy >= 13u) continue;
#pragma unroll
            for (int kx = 0; kx < 3; ++kx) {
              const int x2 = xx + kx - 1;
              if ((unsigned)x2 >= 13u) continue;
              dw += dwc_w[c * 9 + ky * 3 + kx] * ld2s(sm, OFF_V, 384, d, yy * 13 + x2);
            }
          }
          o2[mi][dt][r] += dw;       // act value in regs
        }
      }
    }
    __syncthreads();                 // all dwconv reads of Vt done

    // ---- write act [n][d] over Vt region + stage Wproj over Q/K region ----
#pragma unroll
    for (int mi = 0; mi < 2; ++mi) {
      const int mt = wave * 2 + mi;
      if (mt >= 11) continue;
#pragma unroll
      for (int dt = 0; dt < 4; ++dt) {
        const int d = dt * 16 + l15;
#pragma unroll
        for (int r = 0; r < 4; ++r)
          st2s(sm, OFF_V, 128, mt * 16 + l4 * 4 + r, d, f2bf(o2[mi][dt][r]));
      }
    }
    for (int idx = tid; idx < 2048; idx += 384) {
      const int j = idx >> 3;          // 0..255
      const int c8 = idx & 7;
      const float* src = proj_w + j * 256 + h * 64 + c8 * 8;
      float4 f0 = *(const float4*)(src);
      float4 f1 = *(const float4*)(src + 4);
      *(bf16x8*)(sm + OFF_Q + j * 128 + ((c8 * 16) ^ ((j & 7) << 4))) = cvt8(f0, f1);
    }
    __syncthreads();

    // ---- proj partial MFMA: out (+)= act @ Wproj^T (K=64), fp32 RMW ----
#pragma unroll
    for (int mi = 0; mi < 2; ++mi) {
      const int mt = wave * 2 + mi;
      if (mt >= 11) continue;
      const int arow = mt * 16 + l15;
      bf16x8 af0 = ld8s(sm, OFF_V, 128, arow, l4 * 16);
      bf16x8 af1 = ld8s(sm, OFF_V, 128, arow, 64 + l4 * 16);
#pragma unroll
      for (int nt = 0; nt < 16; ++nt) {
        const int brow = nt * 16 + l15;
        bf16x8 bf0 = ld8s(sm, OFF_Q, 128, brow, l4 * 16);
        bf16x8 bf1 = ld8s(sm, OFF_Q, 128, brow, 64 + l4 * 16);
        f32x4 c = z;
        c = mfma16(af0, bf0, c);
        c = mfma16(af1, bf1, c);
        const int col = nt * 16 + l15;
#pragma unroll
        for (int r = 0; r < 4; ++r) {
          const int n = mt * 16 + l4 * 4 + r;
          if (n < 169) {
            float* p = out + ((size_t)b * 169 + n) * 256 + col;
            if (h == 0)      *p = c[r] + proj_b[col];
            else if (h == 3) __builtin_nontemporal_store(*p + c[r], p);
            else             *p += c[r];
          }
        }
      }
    }
    // next head's loop-top barrier protects Q/K/V regions
  }
}

extern "C" void kernel_launch(void* const* d_in, const int* in_sizes, int n_in,
                              void* d_out, int out_size, void* d_ws, size_t ws_size,
                              hipStream_t stream) {
  const float* x      = (const float*)d_in[0];
  const float* qkv_w  = (const float*)d_in[1];
  const float* proj_w = (const float*)d_in[2];
  const float* proj_b = (const float*)d_in[3];
  const float* dwc_w  = (const float*)d_in[4];
  const float* dwc_b  = (const float*)d_in[5];
  const float* an     = (const float*)d_in[6];
  const float* na     = (const float*)d_in[7];
  const float* ah     = (const float*)d_in[8];
  const float* aw     = (const float*)d_in[9];
  const float* ha     = (const float*)d_in[10];
  const float* wa     = (const float*)d_in[11];

  attn_kernel<<<1024, 384, 0, stream>>>(
      x, qkv_w, proj_w, proj_b, dwc_w, dwc_b,
      an, ah, aw, na, ha, wa, (float*)d_out);
}

// Round 11
// 3445.935 us; speedup vs baseline: 1.7806x; 1.1704x over previous
//
#include <hip/hip_runtime.h>

// Round 11: round 10 (green) with ONE change: __launch_bounds__(384,1) instead
// of (384,3). Rationale: LDS (79,360B) caps us at 1 block/CU regardless, so the
// 3-waves/EU hint bought no occupancy but squeezed the kernel to 84 VGPRs --
// at which point the compiler serializes loads (observed 605K cycles/head-iter
// = the fully-serialized floor). Raising the VGPR ceiling lets the scheduler
// keep many independent loads in flight (QKV weight frags, bias gathers).

typedef __attribute__((ext_vector_type(8))) short bf16x8;
typedef __attribute__((ext_vector_type(4))) float f32x4;

#define OFF_Q 0          // Q [176][64] bf16 stride 128 swizzled; Wproj[256][64] overlays 0..32768
#define OFF_K 22528      // K [176][64] stride 128 swizzled; avT [64][192] stride 384 overlays (24576B)
#define OFF_V 47104      // Vt [64][192] stride 384 swizzled; act [176][64] stride 128 overlays
#define OFF_T 71680      // P_tmp: per wave 1280B = [16][40] bf16 stride 80 (no swizzle)
#define SMEM_BYTES 79360

__device__ __forceinline__ unsigned short f2bf(float f) {
  unsigned int u = __float_as_uint(f);
  u += 0x7FFFu + ((u >> 16) & 1u);
  return (unsigned short)(u >> 16);
}
__device__ __forceinline__ float bf2f(unsigned short v) {
  return __uint_as_float(((unsigned int)v) << 16);
}
__device__ __forceinline__ f32x4 mfma16(bf16x8 a, bf16x8 b, f32x4 c) {
  return __builtin_amdgcn_mfma_f32_16x16x32_bf16(a, b, c, 0, 0, 0);
}
__device__ __forceinline__ bf16x8 cvt8(float4 a, float4 b) {
  bf16x8 v;
  v[0] = (short)f2bf(a.x); v[1] = (short)f2bf(a.y);
  v[2] = (short)f2bf(a.z); v[3] = (short)f2bf(a.w);
  v[4] = (short)f2bf(b.x); v[5] = (short)f2bf(b.y);
  v[6] = (short)f2bf(b.z); v[7] = (short)f2bf(b.w);
  return v;
}
__device__ __forceinline__ bf16x8 ld8s(const char* sm, int base, int stride, int row, int colbyte) {
  return *(const bf16x8*)(sm + base + row * stride + (colbyte ^ ((row & 7) << 4)));
}
__device__ __forceinline__ void st2s(char* sm, int base, int stride, int row, int col, unsigned short v) {
  *(unsigned short*)(sm + base + row * stride + ((col * 2) ^ ((row & 7) << 4))) = v;
}
__device__ __forceinline__ float ld2s(const char* sm, int base, int stride, int row, int col) {
  return bf2f(*(const unsigned short*)(sm + base + row * stride + ((col * 2) ^ ((row & 7) << 4))));
}

__global__ __launch_bounds__(384, 1) void attn_kernel(
    const float* __restrict__ x, const float* __restrict__ qkv_w,
    const float* __restrict__ proj_w, const float* __restrict__ proj_b,
    const float* __restrict__ dwc_w, const float* __restrict__ dwc_b,
    const float* __restrict__ an, const float* __restrict__ ah,
    const float* __restrict__ aw, const float* __restrict__ na,
    const float* __restrict__ ha, const float* __restrict__ wa,
    float* __restrict__ out)
{
  __shared__ __align__(16) char sm[SMEM_BYTES];
  const int b = blockIdx.x;
  const int tid = threadIdx.x;
  const int wave = tid >> 6;
  const int lane = tid & 63;
  const int l15 = lane & 15;
  const int l4 = lane >> 4;
  const int mt0 = wave * 2;
  const int mt1 = wave * 2 + 1;   // ==11 for wave 5 -> skipped
  const float* xb = x + (size_t)b * 169 * 256;
  const f32x4 z = {0.f, 0.f, 0.f, 0.f};

  // one-time LDS zero: pad bytes must never decode to Inf/NaN (0 x NaN = NaN)
  {
    int* p = (int*)sm;
    for (int i = tid; i < SMEM_BYTES / 4; i += 384) p[i] = 0;
  }

  // fused S-phase (in-reg softmax) + PV via per-wave P_tmp.
  auto fused = [&](int sBase, int pvBase, int which, int h, f32x4 (&o_all)[2][4]) {
#pragma unroll
    for (int mi = 0; mi < 2; ++mi) {
#pragma unroll
      for (int dt = 0; dt < 4; ++dt) o_all[mi][dt] = z;
      const int mt = wave * 2 + mi;
      if (mt >= 11) continue;
      const int arow = mt * 16 + l15;
      const int rbase = mt * 16 + l4 * 4;
      bf16x8 a0 = ld8s(sm, OFF_Q, 128, arow, l4 * 16);
      bf16x8 a1 = ld8s(sm, OFF_Q, 128, arow, 64 + l4 * 16);
      f32x4 s[11];
#pragma unroll
      for (int nt = 0; nt < 11; ++nt) {
        const int brow = nt * 16 + l15;
        bf16x8 b0 = ld8s(sm, sBase, 128, brow, l4 * 16);
        bf16x8 b1 = ld8s(sm, sBase, 128, brow, 64 + l4 * 16);
        f32x4 c = z;
        c = mfma16(a0, b0, c);
        c = mfma16(a1, b1, c);
        s[nt] = c;
      }
      // bias + mask
#pragma unroll
      for (int nt = 0; nt < 11; ++nt) {
        const int cc = nt * 16 + l15;
        const int ccl = cc > 168 ? 168 : cc;
        const int yc = (ccl * 79) >> 10;
        const int xc = ccl - yc * 13;
#pragma unroll
        for (int r = 0; r < 4; ++r) {
          const int rr = rbase + r;
          const int rrl = rr > 168 ? 168 : rr;
          float bias;
          if (which == 0) {
            bias = an[h * 28561 + rrl * 169 + ccl]
                 + ah[(h * 169 + rrl) * 13 + yc]
                 + aw[(h * 169 + rrl) * 13 + xc];
          } else {
            const int yn = (rrl * 79) >> 10;
            const int xn = rrl - yn * 13;
            bias = na[h * 28561 + ccl * 169 + rrl]
                 + ha[(h * 13 + yn) * 169 + ccl]
                 + wa[(h * 13 + xn) * 169 + ccl];
          }
          const float v = s[nt][r] * 0.125f + bias;
          s[nt][r] = (cc > 168) ? -3.0e38f : v;
        }
      }
      // in-register softmax
#pragma unroll
      for (int r = 0; r < 4; ++r) {
        float m = s[0][r];
#pragma unroll
        for (int nt = 1; nt < 11; ++nt) m = fmaxf(m, s[nt][r]);
        m = fmaxf(m, __shfl_xor(m, 1));
        m = fmaxf(m, __shfl_xor(m, 2));
        m = fmaxf(m, __shfl_xor(m, 4));
        m = fmaxf(m, __shfl_xor(m, 8));
        float sum = 0.f;
#pragma unroll
        for (int nt = 0; nt < 11; ++nt) { const float e = __expf(s[nt][r] - m); s[nt][r] = e; sum += e; }
        sum += __shfl_xor(sum, 1);
        sum += __shfl_xor(sum, 2);
        sum += __shfl_xor(sum, 4);
        sum += __shfl_xor(sum, 8);
        const float inv = 1.f / sum;
#pragma unroll
        for (int nt = 0; nt < 11; ++nt) s[nt][r] *= inv;
      }
      // PV: per 32-wide chunk pair, round-trip through per-wave P_tmp
      const int tb = OFF_T + wave * 1280;
#pragma unroll
      for (int np = 0; np < 6; ++np) {
        const int nt1 = 2 * np + 1;
#pragma unroll
        for (int r = 0; r < 4; ++r) {
          char* prow = sm + tb + (l4 * 4 + r) * 80;
          *(unsigned short*)(prow + l15 * 2) = f2bf(s[2 * np][r]);
          *(unsigned short*)(prow + 32 + l15 * 2) =
              (nt1 < 11) ? f2bf(s[nt1][r]) : (unsigned short)0;
        }
        bf16x8 af = *(const bf16x8*)(sm + tb + l15 * 80 + l4 * 16);
#pragma unroll
        for (int dt = 0; dt < 4; ++dt) {
          bf16x8 bv = ld8s(sm, pvBase, 384, dt * 16 + l15, np * 64 + l4 * 16);
          o_all[mi][dt] = mfma16(af, bv, o_all[mi][dt]);
        }
      }
    }
  };

  for (int h = 0; h < 4; ++h) {
    __syncthreads();   // previous head fully consumed (and initial zero done)

    // ---- QKV: [176 x 192] = x[b] @ w_head^T, direct-global frags, 0 barriers ----
    {
      f32x4 acc0[12], acc1[12];
#pragma unroll
      for (int i = 0; i < 12; ++i) { acc0[i] = z; acc1[i] = z; }
      const int arow0 = mt0 * 16 + l15;
      const int arow1 = mt1 * 16 + l15;
      const int gr0 = arow0 < 169 ? arow0 : 168;
      const int gr1 = arow1 < 169 ? arow1 : 168;

      for (int ks = 0; ks < 8; ++ks) {
        bf16x8 af0, af1;
        {
          const float* p0 = xb + gr0 * 256 + ks * 32 + l4 * 8;
          af0 = cvt8(*(const float4*)p0, *(const float4*)(p0 + 4));
        }
        {
          const float* p1 = xb + gr1 * 256 + ks * 32 + l4 * 8;
          af1 = cvt8(*(const float4*)p1, *(const float4*)(p1 + 4));
        }
#pragma unroll
        for (int nt = 0; nt < 12; ++nt) {
          const int wrow = nt * 16 + l15;
          const int grow = ((wrow >> 6) << 8) + h * 64 + (wrow & 63);
          const float* wp = qkv_w + grow * 256 + ks * 32 + l4 * 8;
          bf16x8 bw = cvt8(*(const float4*)wp, *(const float4*)(wp + 4));
          acc0[nt] = mfma16(af0, bw, acc0[nt]);
          if (mt1 < 11) acc1[nt] = mfma16(af1, bw, acc1[nt]);
        }
      }
      // write Q,K row-major [n][d] (stride 128, swz); V transposed [d][n] (stride 384, swz)
#pragma unroll
      for (int nt = 0; nt < 12; ++nt) {
        const int mat = nt >> 2;
        const int d = (nt & 3) * 16 + l15;
#pragma unroll
        for (int r = 0; r < 4; ++r) {
          {
            const int n = mt0 * 16 + l4 * 4 + r;
            const unsigned short u = f2bf(acc0[nt][r]);
            if (mat == 0)      st2s(sm, OFF_Q, 128, n, d, u);
            else if (mat == 1) st2s(sm, OFF_K, 128, n, d, u);
            else               st2s(sm, OFF_V, 384, d, n, u);
          }
          if (mt1 < 11) {
            const int n = mt1 * 16 + l4 * 4 + r;
            const unsigned short u = f2bf(acc1[nt][r]);
            if (mat == 0)      st2s(sm, OFF_Q, 128, n, d, u);
            else if (mat == 1) st2s(sm, OFF_K, 128, n, d, u);
            else               st2s(sm, OFF_V, 384, d, n, u);
          }
        }
      }
    }
    __syncthreads();

    // ---- S1 + P1V fused (B=K, PV-B=Vt) -> agent_v rows in regs ----
    f32x4 o1[2][4];
    fused(OFF_K, OFF_V, 0, h, o1);
    __syncthreads();                 // all S1 reads of K done
    // write avT [d][a] over K region
#pragma unroll
    for (int mi = 0; mi < 2; ++mi) {
      const int mt = wave * 2 + mi;
      if (mt >= 11) continue;
#pragma unroll
      for (int dt = 0; dt < 4; ++dt)
#pragma unroll
        for (int r = 0; r < 4; ++r)
          st2s(sm, OFF_K, 384, dt * 16 + l15, mt * 16 + l4 * 4 + r, f2bf(o1[mi][dt][r]));
    }
    __syncthreads();

    // ---- S2 + P2A fused (B=Q, PV-B=avT) + dwconv epilogue (reads Vt) ----
    f32x4 o2[2][4];
    fused(OFF_Q, OFF_K, 1, h, o2);
#pragma unroll
    for (int mi = 0; mi < 2; ++mi) {
      const int mt = wave * 2 + mi;
      if (mt >= 11) continue;
#pragma unroll
      for (int dt = 0; dt < 4; ++dt) {
        const int d = dt * 16 + l15;
        const int c = h * 64 + d;
        const float bc = dwc_b[c];
#pragma unroll
        for (int r = 0; r < 4; ++r) {
          const int n = mt * 16 + l4 * 4 + r;
          const int nl = n > 168 ? 168 : n;
          const int y = (nl * 79) >> 10;
          const int xx = nl - y * 13;
          float dw = bc;
#pragma unroll
          for (int ky = 0; ky < 3; ++ky) {
            const int yy = y + ky - 1;
            if ((unsigned)yy >= 13u) continue;
#pragma unroll
            for (int kx = 0; kx < 3; ++kx) {
              const int x2 = xx + kx - 1;
              if ((unsigned)x2 >= 13u) continue;
              dw += dwc_w[c * 9 + ky * 3 + kx] * ld2s(sm, OFF_V, 384, d, yy * 13 + x2);
            }
          }
          o2[mi][dt][r] += dw;       // act value in regs
        }
      }
    }
    __syncthreads();                 // all dwconv reads of Vt done

    // ---- write act [n][d] over Vt region + stage Wproj over Q/K region ----
#pragma unroll
    for (int mi = 0; mi < 2; ++mi) {
      const int mt = wave * 2 + mi;
      if (mt >= 11) continue;
#pragma unroll
      for (int dt = 0; dt < 4; ++dt) {
        const int d = dt * 16 + l15;
#pragma unroll
        for (int r = 0; r < 4; ++r)
          st2s(sm, OFF_V, 128, mt * 16 + l4 * 4 + r, d, f2bf(o2[mi][dt][r]));
      }
    }
    for (int idx = tid; idx < 2048; idx += 384) {
      const int j = idx >> 3;          // 0..255
      const int c8 = idx & 7;
      const float* src = proj_w + j * 256 + h * 64 + c8 * 8;
      float4 f0 = *(const float4*)(src);
      float4 f1 = *(const float4*)(src + 4);
      *(bf16x8*)(sm + OFF_Q + j * 128 + ((c8 * 16) ^ ((j & 7) << 4))) = cvt8(f0, f1);
    }
    __syncthreads();

    // ---- proj partial MFMA: out (+)= act @ Wproj^T (K=64), fp32 RMW ----
#pragma unroll
    for (int mi = 0; mi < 2; ++mi) {
      const int mt = wave * 2 + mi;
      if (mt >= 11) continue;
      const int arow = mt * 16 + l15;
      bf16x8 af0 = ld8s(sm, OFF_V, 128, arow, l4 * 16);
      bf16x8 af1 = ld8s(sm, OFF_V, 128, arow, 64 + l4 * 16);
#pragma unroll
      for (int nt = 0; nt < 16; ++nt) {
        const int brow = nt * 16 + l15;
        bf16x8 bf0 = ld8s(sm, OFF_Q, 128, brow, l4 * 16);
        bf16x8 bf1 = ld8s(sm, OFF_Q, 128, brow, 64 + l4 * 16);
        f32x4 c = z;
        c = mfma16(af0, bf0, c);
        c = mfma16(af1, bf1, c);
        const int col = nt * 16 + l15;
#pragma unroll
        for (int r = 0; r < 4; ++r) {
          const int n = mt * 16 + l4 * 4 + r;
          if (n < 169) {
            float* p = out + ((size_t)b * 169 + n) * 256 + col;
            if (h == 0)      *p = c[r] + proj_b[col];
            else if (h == 3) __builtin_nontemporal_store(*p + c[r], p);
            else             *p += c[r];
          }
        }
      }
    }
    // next head's loop-top barrier protects Q/K/V regions
  }
}

extern "C" void kernel_launch(void* const* d_in, const int* in_sizes, int n_in,
                              void* d_out, int out_size, void* d_ws, size_t ws_size,
                              hipStream_t stream) {
  const float* x      = (const float*)d_in[0];
  const float* qkv_w  = (const float*)d_in[1];
  const float* proj_w = (const float*)d_in[2];
  const float* proj_b = (const float*)d_in[3];
  const float* dwc_w  = (const float*)d_in[4];
  const float* dwc_b  = (const float*)d_in[5];
  const float* an     = (const float*)d_in[6];
  const float* na     = (const float*)d_in[7];
  const float* ah     = (const float*)d_in[8];
  const float* aw     = (const float*)d_in[9];
  const float* ha     = (const float*)d_in[10];
  const float* wa     = (const float*)d_in[11];

  attn_kernel<<<1024, 384, 0, stream>>>(
      x, qkv_w, proj_w, proj_b, dwc_w, dwc_b,
      an, ah, aw, na, ha, wa, (float*)d_out);
}

// Round 13
// 3380.383 us; speedup vs baseline: 1.8151x; 1.0194x over previous
//
#include <hip/hip_runtime.h>

// Round 13: round 12's red was a swizzle-bijectivity violation: the XOR
// ((row&7)<<4) flips byte bits 4-6, closed only within 128B-aligned windows;
// stride 352 is not a multiple of 128, so swizzled writes in the last 96B of
// a row stomped the next row's first 32B. Fix: Vt/avT (stride 352) are now
// PLAIN (no swizzle) -- natural 352B stride spreads banks period-4 anyway.
// Q/K/act keep the valid 128-stride swizzle. LDS stays 74,496B (2-block bid).

typedef __attribute__((ext_vector_type(8))) short bf16x8;
typedef __attribute__((ext_vector_type(4))) float f32x4;

#define OFF_Q 0          // Q [176][64] bf16 stride 128 swizzled; Wproj[256][64]@128 overlays 0..32768
#define OFF_K 22528      // K [176][64] stride 128 swizzled; avT [64][176]@352 PLAIN overlays exactly
#define OFF_V 45056      // Vt [64][176]@352 PLAIN; act [176][64]@128 swizzled overlays
#define OFF_T 67584      // P_tmp: per wave 1152B = [16][36 bf16] stride 72 (no swizzle)
#define SMEM_BYTES 74496

__device__ __forceinline__ unsigned short f2bf(float f) {
  unsigned int u = __float_as_uint(f);
  u += 0x7FFFu + ((u >> 16) & 1u);
  return (unsigned short)(u >> 16);
}
__device__ __forceinline__ float bf2f(unsigned short v) {
  return __uint_as_float(((unsigned int)v) << 16);
}
__device__ __forceinline__ f32x4 mfma16(bf16x8 a, bf16x8 b, f32x4 c) {
  return __builtin_amdgcn_mfma_f32_16x16x32_bf16(a, b, c, 0, 0, 0);
}
__device__ __forceinline__ bf16x8 cvt8(float4 a, float4 b) {
  bf16x8 v;
  v[0] = (short)f2bf(a.x); v[1] = (short)f2bf(a.y);
  v[2] = (short)f2bf(a.z); v[3] = (short)f2bf(a.w);
  v[4] = (short)f2bf(b.x); v[5] = (short)f2bf(b.y);
  v[6] = (short)f2bf(b.z); v[7] = (short)f2bf(b.w);
  return v;
}
// swizzled (stride must be multiple of 128)
__device__ __forceinline__ bf16x8 ld8s(const char* sm, int base, int stride, int row, int colbyte) {
  return *(const bf16x8*)(sm + base + row * stride + (colbyte ^ ((row & 7) << 4)));
}
__device__ __forceinline__ void st2s(char* sm, int base, int stride, int row, int col, unsigned short v) {
  *(unsigned short*)(sm + base + row * stride + ((col * 2) ^ ((row & 7) << 4))) = v;
}
// plain (any stride)
__device__ __forceinline__ bf16x8 ld8p(const char* sm, int base, int stride, int row, int colbyte) {
  return *(const bf16x8*)(sm + base + row * stride + colbyte);
}
__device__ __forceinline__ void st2p(char* sm, int base, int stride, int row, int col, unsigned short v) {
  *(unsigned short*)(sm + base + row * stride + col * 2) = v;
}
__device__ __forceinline__ float ld2p(const char* sm, int base, int stride, int row, int col) {
  return bf2f(*(const unsigned short*)(sm + base + row * stride + col * 2));
}

__global__ __launch_bounds__(384, 1) void attn_kernel(
    const float* __restrict__ x, const float* __restrict__ qkv_w,
    const float* __restrict__ proj_w, const float* __restrict__ proj_b,
    const float* __restrict__ dwc_w, const float* __restrict__ dwc_b,
    const float* __restrict__ an, const float* __restrict__ ah,
    const float* __restrict__ aw, const float* __restrict__ na,
    const float* __restrict__ ha, const float* __restrict__ wa,
    float* __restrict__ out)
{
  __shared__ __align__(16) char sm[SMEM_BYTES];
  const int b = blockIdx.x;
  const int tid = threadIdx.x;
  const int wave = tid >> 6;
  const int lane = tid & 63;
  const int l15 = lane & 15;
  const int l4 = lane >> 4;
  const int mt0 = wave * 2;
  const int mt1 = wave * 2 + 1;   // ==11 for wave 5 -> skipped
  const float* xb = x + (size_t)b * 169 * 256;
  const f32x4 z = {0.f, 0.f, 0.f, 0.f};

  // one-time LDS zero: stray pad bytes must never decode to Inf/NaN
  {
    int* p = (int*)sm;
    for (int i = tid; i < SMEM_BYTES / 4; i += 384) p[i] = 0;
  }

  // fused S-phase (in-reg softmax) + PV via per-wave P_tmp.
  auto fused = [&](int sBase, int pvBase, int which, int h, f32x4 (&o_all)[2][4]) {
#pragma unroll
    for (int mi = 0; mi < 2; ++mi) {
#pragma unroll
      for (int dt = 0; dt < 4; ++dt) o_all[mi][dt] = z;
      const int mt = wave * 2 + mi;
      if (mt >= 11) continue;
      const int arow = mt * 16 + l15;
      const int rbase = mt * 16 + l4 * 4;
      bf16x8 a0 = ld8s(sm, OFF_Q, 128, arow, l4 * 16);
      bf16x8 a1 = ld8s(sm, OFF_Q, 128, arow, 64 + l4 * 16);
      f32x4 s[11];
#pragma unroll
      for (int nt = 0; nt < 11; ++nt) {
        const int brow = nt * 16 + l15;
        bf16x8 b0 = ld8s(sm, sBase, 128, brow, l4 * 16);
        bf16x8 b1 = ld8s(sm, sBase, 128, brow, 64 + l4 * 16);
        f32x4 c = z;
        c = mfma16(a0, b0, c);
        c = mfma16(a1, b1, c);
        s[nt] = c;
      }
      // bias + mask
#pragma unroll
      for (int nt = 0; nt < 11; ++nt) {
        const int cc = nt * 16 + l15;
        const int ccl = cc > 168 ? 168 : cc;
        const int yc = (ccl * 79) >> 10;
        const int xc = ccl - yc * 13;
#pragma unroll
        for (int r = 0; r < 4; ++r) {
          const int rr = rbase + r;
          const int rrl = rr > 168 ? 168 : rr;
          float bias;
          if (which == 0) {
            bias = an[h * 28561 + rrl * 169 + ccl]
                 + ah[(h * 169 + rrl) * 13 + yc]
                 + aw[(h * 169 + rrl) * 13 + xc];
          } else {
            const int yn = (rrl * 79) >> 10;
            const int xn = rrl - yn * 13;
            bias = na[h * 28561 + ccl * 169 + rrl]
                 + ha[(h * 13 + yn) * 169 + ccl]
                 + wa[(h * 13 + xn) * 169 + ccl];
          }
          const float v = s[nt][r] * 0.125f + bias;
          s[nt][r] = (cc > 168) ? -3.0e38f : v;
        }
      }
      // in-register softmax
#pragma unroll
      for (int r = 0; r < 4; ++r) {
        float m = s[0][r];
#pragma unroll
        for (int nt = 1; nt < 11; ++nt) m = fmaxf(m, s[nt][r]);
        m = fmaxf(m, __shfl_xor(m, 1));
        m = fmaxf(m, __shfl_xor(m, 2));
        m = fmaxf(m, __shfl_xor(m, 4));
        m = fmaxf(m, __shfl_xor(m, 8));
        float sum = 0.f;
#pragma unroll
        for (int nt = 0; nt < 11; ++nt) { const float e = __expf(s[nt][r] - m); s[nt][r] = e; sum += e; }
        sum += __shfl_xor(sum, 1);
        sum += __shfl_xor(sum, 2);
        sum += __shfl_xor(sum, 4);
        sum += __shfl_xor(sum, 8);
        const float inv = 1.f / sum;
#pragma unroll
        for (int nt = 0; nt < 11; ++nt) s[nt][r] *= inv;
      }
      // PV: per 32-wide chunk pair, round-trip through per-wave P_tmp
      const int tb = OFF_T + wave * 1152;
#pragma unroll
      for (int np = 0; np < 6; ++np) {
        const int nt1 = 2 * np + 1;
#pragma unroll
        for (int r = 0; r < 4; ++r) {
          char* prow = sm + tb + (l4 * 4 + r) * 72;
          *(unsigned short*)(prow + l15 * 2) = f2bf(s[2 * np][r]);
          *(unsigned short*)(prow + 32 + l15 * 2) =
              (nt1 < 11) ? f2bf(s[nt1][r]) : (unsigned short)0;
        }
        bf16x8 af = *(const bf16x8*)(sm + tb + l15 * 72 + l4 * 16);
#pragma unroll
        for (int dt = 0; dt < 4; ++dt) {
          bf16x8 bv = ld8p(sm, pvBase, 352, dt * 16 + l15, np * 64 + l4 * 16);
          o_all[mi][dt] = mfma16(af, bv, o_all[mi][dt]);
        }
      }
    }
  };

  for (int h = 0; h < 4; ++h) {
    __syncthreads();   // previous head fully consumed (and initial zero done)

    // ---- QKV: [176 x 192] = x[b] @ w_head^T, direct-global frags, 0 barriers ----
    {
      f32x4 acc0[12], acc1[12];
#pragma unroll
      for (int i = 0; i < 12; ++i) { acc0[i] = z; acc1[i] = z; }
      const int arow0 = mt0 * 16 + l15;
      const int arow1 = mt1 * 16 + l15;
      const int gr0 = arow0 < 169 ? arow0 : 168;
      const int gr1 = arow1 < 169 ? arow1 : 168;

      for (int ks = 0; ks < 8; ++ks) {
        bf16x8 af0, af1;
        {
          const float* p0 = xb + gr0 * 256 + ks * 32 + l4 * 8;
          af0 = cvt8(*(const float4*)p0, *(const float4*)(p0 + 4));
        }
        {
          const float* p1 = xb + gr1 * 256 + ks * 32 + l4 * 8;
          af1 = cvt8(*(const float4*)p1, *(const float4*)(p1 + 4));
        }
#pragma unroll
        for (int nt = 0; nt < 12; ++nt) {
          const int wrow = nt * 16 + l15;
          const int grow = ((wrow >> 6) << 8) + h * 64 + (wrow & 63);
          const float* wp = qkv_w + grow * 256 + ks * 32 + l4 * 8;
          bf16x8 bw = cvt8(*(const float4*)wp, *(const float4*)(wp + 4));
          acc0[nt] = mfma16(af0, bw, acc0[nt]);
          if (mt1 < 11) acc1[nt] = mfma16(af1, bw, acc1[nt]);
        }
      }
      // write Q,K row-major [n][d] (stride 128, swz); V transposed [d][n] (stride 352, plain)
#pragma unroll
      for (int nt = 0; nt < 12; ++nt) {
        const int mat = nt >> 2;
        const int d = (nt & 3) * 16 + l15;
#pragma unroll
        for (int r = 0; r < 4; ++r) {
          {
            const int n = mt0 * 16 + l4 * 4 + r;
            const unsigned short u = f2bf(acc0[nt][r]);
            if (mat == 0)      st2s(sm, OFF_Q, 128, n, d, u);
            else if (mat == 1) st2s(sm, OFF_K, 128, n, d, u);
            else               st2p(sm, OFF_V, 352, d, n, u);
          }
          if (mt1 < 11) {
            const int n = mt1 * 16 + l4 * 4 + r;
            const unsigned short u = f2bf(acc1[nt][r]);
            if (mat == 0)      st2s(sm, OFF_Q, 128, n, d, u);
            else if (mat == 1) st2s(sm, OFF_K, 128, n, d, u);
            else               st2p(sm, OFF_V, 352, d, n, u);
          }
        }
      }
    }
    __syncthreads();

    // ---- S1 + P1V fused (B=K, PV-B=Vt) -> agent_v rows in regs ----
    f32x4 o1[2][4];
    fused(OFF_K, OFF_V, 0, h, o1);
    __syncthreads();                 // all S1 reads of K done
    // write avT [d][a] over K region (stride 352, plain)
#pragma unroll
    for (int mi = 0; mi < 2; ++mi) {
      const int mt = wave * 2 + mi;
      if (mt >= 11) continue;
#pragma unroll
      for (int dt = 0; dt < 4; ++dt)
#pragma unroll
        for (int r = 0; r < 4; ++r)
          st2p(sm, OFF_K, 352, dt * 16 + l15, mt * 16 + l4 * 4 + r, f2bf(o1[mi][dt][r]));
    }
    __syncthreads();

    // ---- S2 + P2A fused (B=Q, PV-B=avT) + dwconv epilogue (reads Vt) ----
    f32x4 o2[2][4];
    fused(OFF_Q, OFF_K, 1, h, o2);
#pragma unroll
    for (int mi = 0; mi < 2; ++mi) {
      const int mt = wave * 2 + mi;
      if (mt >= 11) continue;
#pragma unroll
      for (int dt = 0; dt < 4; ++dt) {
        const int d = dt * 16 + l15;
        const int c = h * 64 + d;
        const float bc = dwc_b[c];
#pragma unroll
        for (int r = 0; r < 4; ++r) {
          const int n = mt * 16 + l4 * 4 + r;
          const int nl = n > 168 ? 168 : n;
          const int y = (nl * 79) >> 10;
          const int xx = nl - y * 13;
          float dw = bc;
#pragma unroll
          for (int ky = 0; ky < 3; ++ky) {
            const int yy = y + ky - 1;
            if ((unsigned)yy >= 13u) continue;
#pragma unroll
            for (int kx = 0; kx < 3; ++kx) {
              const int x2 = xx + kx - 1;
              if ((unsigned)x2 >= 13u) continue;
              dw += dwc_w[c * 9 + ky * 3 + kx] * ld2p(sm, OFF_V, 352, d, yy * 13 + x2);
            }
          }
          o2[mi][dt][r] += dw;       // act value in regs
        }
      }
    }
    __syncthreads();                 // all dwconv reads of Vt done

    // ---- write act [n][d] over Vt region (stride 128, swz) + stage Wproj ----
#pragma unroll
    for (int mi = 0; mi < 2; ++mi) {
      const int mt = wave * 2 + mi;
      if (mt >= 11) continue;
#pragma unroll
      for (int dt = 0; dt < 4; ++dt) {
        const int d = dt * 16 + l15;
#pragma unroll
        for (int r = 0; r < 4; ++r)
          st2s(sm, OFF_V, 128, mt * 16 + l4 * 4 + r, d, f2bf(o2[mi][dt][r]));
      }
    }
    for (int idx = tid; idx < 2048; idx += 384) {
      const int j = idx >> 3;          // 0..255
      const int c8 = idx & 7;
      const float* src = proj_w + j * 256 + h * 64 + c8 * 8;
      float4 f0 = *(const float4*)(src);
      float4 f1 = *(const float4*)(src + 4);
      *(bf16x8*)(sm + OFF_Q + j * 128 + ((c8 * 16) ^ ((j & 7) << 4))) = cvt8(f0, f1);
    }
    __syncthreads();

    // ---- proj partial MFMA: out (+)= act @ Wproj^T (K=64), fp32 RMW ----
#pragma unroll
    for (int mi = 0; mi < 2; ++mi) {
      const int mt = wave * 2 + mi;
      if (mt >= 11) continue;
      const int arow = mt * 16 + l15;
      bf16x8 af0 = ld8s(sm, OFF_V, 128, arow, l4 * 16);
      bf16x8 af1 = ld8s(sm, OFF_V, 128, arow, 64 + l4 * 16);
#pragma unroll
      for (int nt = 0; nt < 16; ++nt) {
        const int brow = nt * 16 + l15;
        bf16x8 bf0 = ld8s(sm, OFF_Q, 128, brow, l4 * 16);
        bf16x8 bf1 = ld8s(sm, OFF_Q, 128, brow, 64 + l4 * 16);
        f32x4 c = z;
        c = mfma16(af0, bf0, c);
        c = mfma16(af1, bf1, c);
        const int col = nt * 16 + l15;
#pragma unroll
        for (int r = 0; r < 4; ++r) {
          const int n = mt * 16 + l4 * 4 + r;
          if (n < 169) {
            float* p = out + ((size_t)b * 169 + n) * 256 + col;
            if (h == 0)      *p = c[r] + proj_b[col];
            else if (h == 3) __builtin_nontemporal_store(*p + c[r], p);
            else             *p += c[r];
          }
        }
      }
    }
    // next head's loop-top barrier protects Q/K/V regions
  }
}

extern "C" void kernel_launch(void* const* d_in, const int* in_sizes, int n_in,
                              void* d_out, int out_size, void* d_ws, size_t ws_size,
                              hipStream_t stream) {
  const float* x      = (const float*)d_in[0];
  const float* qkv_w  = (const float*)d_in[1];
  const float* proj_w = (const float*)d_in[2];
  const float* proj_b = (const float*)d_in[3];
  const float* dwc_w  = (const float*)d_in[4];
  const float* dwc_b  = (const float*)d_in[5];
  const float* an     = (const float*)d_in[6];
  const float* na     = (const float*)d_in[7];
  const float* ah     = (const float*)d_in[8];
  const float* aw     = (const float*)d_in[9];
  const float* ha     = (const float*)d_in[10];
  const float* wa     = (const float*)d_in[11];

  attn_kernel<<<1024, 384, 0, stream>>>(
      x, qkv_w, proj_w, proj_b, dwc_w, dwc_b,
      an, ah, aw, na, ha, wa, (float*)d_out);
}

// Round 14
// 2598.468 us; speedup vs baseline: 2.3613x; 1.3009x over previous
//
#include <hip/hip_runtime.h>

// Round 14: round 13 (green) with ONE structural lever: 384 -> 768 threads
// (12 waves), ONE m-tile per wave (mt = wave, wave 11 idle in compute).
// Per-wave serial chain halves; resident waves double (3/SIMD) to hide the
// global/bias-gather latencies that dominate. LDS 81,408B (still 1 block/CU,
// proven unavoidable by round 13's failed 2-block bid). Numerics, overlays,
// barriers, RMW epilogue unchanged.

typedef __attribute__((ext_vector_type(8))) short bf16x8;
typedef __attribute__((ext_vector_type(4))) float f32x4;

#define OFF_Q 0          // Q [176][64] bf16 stride 128 swizzled; Wproj[256][64]@128 overlays 0..32768
#define OFF_K 22528      // K [176][64] stride 128 swizzled; avT [64][176]@352 PLAIN overlays exactly
#define OFF_V 45056      // Vt [64][176]@352 PLAIN; act [176][64]@128 swizzled overlays
#define OFF_T 67584      // P_tmp: per wave 1152B = [16][36 bf16] stride 72 (12 waves)
#define SMEM_BYTES 81408

__device__ __forceinline__ unsigned short f2bf(float f) {
  unsigned int u = __float_as_uint(f);
  u += 0x7FFFu + ((u >> 16) & 1u);
  return (unsigned short)(u >> 16);
}
__device__ __forceinline__ float bf2f(unsigned short v) {
  return __uint_as_float(((unsigned int)v) << 16);
}
__device__ __forceinline__ f32x4 mfma16(bf16x8 a, bf16x8 b, f32x4 c) {
  return __builtin_amdgcn_mfma_f32_16x16x32_bf16(a, b, c, 0, 0, 0);
}
__device__ __forceinline__ bf16x8 cvt8(float4 a, float4 b) {
  bf16x8 v;
  v[0] = (short)f2bf(a.x); v[1] = (short)f2bf(a.y);
  v[2] = (short)f2bf(a.z); v[3] = (short)f2bf(a.w);
  v[4] = (short)f2bf(b.x); v[5] = (short)f2bf(b.y);
  v[6] = (short)f2bf(b.z); v[7] = (short)f2bf(b.w);
  return v;
}
// swizzled (stride must be multiple of 128)
__device__ __forceinline__ bf16x8 ld8s(const char* sm, int base, int stride, int row, int colbyte) {
  return *(const bf16x8*)(sm + base + row * stride + (colbyte ^ ((row & 7) << 4)));
}
__device__ __forceinline__ void st2s(char* sm, int base, int stride, int row, int col, unsigned short v) {
  *(unsigned short*)(sm + base + row * stride + ((col * 2) ^ ((row & 7) << 4))) = v;
}
// plain (any stride)
__device__ __forceinline__ bf16x8 ld8p(const char* sm, int base, int stride, int row, int colbyte) {
  return *(const bf16x8*)(sm + base + row * stride + colbyte);
}
__device__ __forceinline__ void st2p(char* sm, int base, int stride, int row, int col, unsigned short v) {
  *(unsigned short*)(sm + base + row * stride + col * 2) = v;
}
__device__ __forceinline__ float ld2p(const char* sm, int base, int stride, int row, int col) {
  return bf2f(*(const unsigned short*)(sm + base + row * stride + col * 2));
}

__global__ __launch_bounds__(768, 1) void attn_kernel(
    const float* __restrict__ x, const float* __restrict__ qkv_w,
    const float* __restrict__ proj_w, const float* __restrict__ proj_b,
    const float* __restrict__ dwc_w, const float* __restrict__ dwc_b,
    const float* __restrict__ an, const float* __restrict__ ah,
    const float* __restrict__ aw, const float* __restrict__ na,
    const float* __restrict__ ha, const float* __restrict__ wa,
    float* __restrict__ out)
{
  __shared__ __align__(16) char sm[SMEM_BYTES];
  const int b = blockIdx.x;
  const int tid = threadIdx.x;
  const int wave = tid >> 6;        // 0..11; mt = wave; wave 11 idle in compute
  const int lane = tid & 63;
  const int l15 = lane & 15;
  const int l4 = lane >> 4;
  const int mt = wave;
  const float* xb = x + (size_t)b * 169 * 256;
  const f32x4 z = {0.f, 0.f, 0.f, 0.f};

  // one-time LDS zero: stray pad bytes must never decode to Inf/NaN
  {
    int* p = (int*)sm;
    for (int i = tid; i < SMEM_BYTES / 4; i += 768) p[i] = 0;
  }

  // fused S-phase (in-reg softmax) + PV via per-wave P_tmp. One m-tile/wave.
  auto fused = [&](int sBase, int pvBase, int which, int h, f32x4 (&o)[4]) {
#pragma unroll
    for (int dt = 0; dt < 4; ++dt) o[dt] = z;
    if (mt >= 11) return;
    const int arow = mt * 16 + l15;
    const int rbase = mt * 16 + l4 * 4;
    bf16x8 a0 = ld8s(sm, OFF_Q, 128, arow, l4 * 16);
    bf16x8 a1 = ld8s(sm, OFF_Q, 128, arow, 64 + l4 * 16);
    f32x4 s[11];
#pragma unroll
    for (int nt = 0; nt < 11; ++nt) {
      const int brow = nt * 16 + l15;
      bf16x8 b0 = ld8s(sm, sBase, 128, brow, l4 * 16);
      bf16x8 b1 = ld8s(sm, sBase, 128, brow, 64 + l4 * 16);
      f32x4 c = z;
      c = mfma16(a0, b0, c);
      c = mfma16(a1, b1, c);
      s[nt] = c;
    }
    // bias + mask
#pragma unroll
    for (int nt = 0; nt < 11; ++nt) {
      const int cc = nt * 16 + l15;
      const int ccl = cc > 168 ? 168 : cc;
      const int yc = (ccl * 79) >> 10;
      const int xc = ccl - yc * 13;
#pragma unroll
      for (int r = 0; r < 4; ++r) {
        const int rr = rbase + r;
        const int rrl = rr > 168 ? 168 : rr;
        float bias;
        if (which == 0) {
          bias = an[h * 28561 + rrl * 169 + ccl]
               + ah[(h * 169 + rrl) * 13 + yc]
               + aw[(h * 169 + rrl) * 13 + xc];
        } else {
          const int yn = (rrl * 79) >> 10;
          const int xn = rrl - yn * 13;
          bias = na[h * 28561 + ccl * 169 + rrl]
               + ha[(h * 13 + yn) * 169 + ccl]
               + wa[(h * 13 + xn) * 169 + ccl];
        }
        const float v = s[nt][r] * 0.125f + bias;
        s[nt][r] = (cc > 168) ? -3.0e38f : v;
      }
    }
    // in-register softmax
#pragma unroll
    for (int r = 0; r < 4; ++r) {
      float m = s[0][r];
#pragma unroll
      for (int nt = 1; nt < 11; ++nt) m = fmaxf(m, s[nt][r]);
      m = fmaxf(m, __shfl_xor(m, 1));
      m = fmaxf(m, __shfl_xor(m, 2));
      m = fmaxf(m, __shfl_xor(m, 4));
      m = fmaxf(m, __shfl_xor(m, 8));
      float sum = 0.f;
#pragma unroll
      for (int nt = 0; nt < 11; ++nt) { const float e = __expf(s[nt][r] - m); s[nt][r] = e; sum += e; }
      sum += __shfl_xor(sum, 1);
      sum += __shfl_xor(sum, 2);
      sum += __shfl_xor(sum, 4);
      sum += __shfl_xor(sum, 8);
      const float inv = 1.f / sum;
#pragma unroll
      for (int nt = 0; nt < 11; ++nt) s[nt][r] *= inv;
    }
    // PV: per 32-wide chunk pair, round-trip through per-wave P_tmp
    const int tb = OFF_T + wave * 1152;
#pragma unroll
    for (int np = 0; np < 6; ++np) {
      const int nt1 = 2 * np + 1;
#pragma unroll
      for (int r = 0; r < 4; ++r) {
        char* prow = sm + tb + (l4 * 4 + r) * 72;
        *(unsigned short*)(prow + l15 * 2) = f2bf(s[2 * np][r]);
        *(unsigned short*)(prow + 32 + l15 * 2) =
            (nt1 < 11) ? f2bf(s[nt1][r]) : (unsigned short)0;
      }
      bf16x8 af = *(const bf16x8*)(sm + tb + l15 * 72 + l4 * 16);
#pragma unroll
      for (int dt = 0; dt < 4; ++dt) {
        bf16x8 bv = ld8p(sm, pvBase, 352, dt * 16 + l15, np * 64 + l4 * 16);
        o[dt] = mfma16(af, bv, o[dt]);
      }
    }
  };

  for (int h = 0; h < 4; ++h) {
    __syncthreads();   // previous head fully consumed (and initial zero done)

    // ---- QKV: [176 x 192] = x[b] @ w_head^T, direct-global frags ----
    if (mt < 11) {
      f32x4 acc[12];
#pragma unroll
      for (int i = 0; i < 12; ++i) acc[i] = z;
      const int arow = mt * 16 + l15;
      const int gr = arow < 169 ? arow : 168;

      for (int ks = 0; ks < 8; ++ks) {
        const float* p0 = xb + gr * 256 + ks * 32 + l4 * 8;
        bf16x8 af = cvt8(*(const float4*)p0, *(const float4*)(p0 + 4));
#pragma unroll
        for (int nt = 0; nt < 12; ++nt) {
          const int wrow = nt * 16 + l15;
          const int grow = ((wrow >> 6) << 8) + h * 64 + (wrow & 63);
          const float* wp = qkv_w + grow * 256 + ks * 32 + l4 * 8;
          bf16x8 bw = cvt8(*(const float4*)wp, *(const float4*)(wp + 4));
          acc[nt] = mfma16(af, bw, acc[nt]);
        }
      }
      // write Q,K row-major (stride 128, swz); V transposed [d][n] (stride 352, plain)
#pragma unroll
      for (int nt = 0; nt < 12; ++nt) {
        const int mat = nt >> 2;
        const int d = (nt & 3) * 16 + l15;
#pragma unroll
        for (int r = 0; r < 4; ++r) {
          const int n = mt * 16 + l4 * 4 + r;
          const unsigned short u = f2bf(acc[nt][r]);
          if (mat == 0)      st2s(sm, OFF_Q, 128, n, d, u);
          else if (mat == 1) st2s(sm, OFF_K, 128, n, d, u);
          else               st2p(sm, OFF_V, 352, d, n, u);
        }
      }
    }
    __syncthreads();

    // ---- S1 + P1V fused (B=K, PV-B=Vt) -> agent_v rows in regs ----
    f32x4 o1[4];
    fused(OFF_K, OFF_V, 0, h, o1);
    __syncthreads();                 // all S1 reads of K done
    // write avT [d][a] over K region (stride 352, plain)
    if (mt < 11) {
#pragma unroll
      for (int dt = 0; dt < 4; ++dt)
#pragma unroll
        for (int r = 0; r < 4; ++r)
          st2p(sm, OFF_K, 352, dt * 16 + l15, mt * 16 + l4 * 4 + r, f2bf(o1[dt][r]));
    }
    __syncthreads();

    // ---- S2 + P2A fused (B=Q, PV-B=avT) + dwconv epilogue (reads Vt) ----
    f32x4 o2[4];
    fused(OFF_Q, OFF_K, 1, h, o2);
    if (mt < 11) {
#pragma unroll
      for (int dt = 0; dt < 4; ++dt) {
        const int d = dt * 16 + l15;
        const int c = h * 64 + d;
        const float bc = dwc_b[c];
#pragma unroll
        for (int r = 0; r < 4; ++r) {
          const int n = mt * 16 + l4 * 4 + r;
          const int nl = n > 168 ? 168 : n;
          const int y = (nl * 79) >> 10;
          const int xx = nl - y * 13;
          float dw = bc;
#pragma unroll
          for (int ky = 0; ky < 3; ++ky) {
            const int yy = y + ky - 1;
            if ((unsigned)yy >= 13u) continue;
#pragma unroll
            for (int kx = 0; kx < 3; ++kx) {
              const int x2 = xx + kx - 1;
              if ((unsigned)x2 >= 13u) continue;
              dw += dwc_w[c * 9 + ky * 3 + kx] * ld2p(sm, OFF_V, 352, d, yy * 13 + x2);
            }
          }
          o2[dt][r] += dw;           // act value in regs
        }
      }
    }
    __syncthreads();                 // all dwconv reads of Vt done

    // ---- write act [n][d] over Vt region (stride 128, swz) + stage Wproj ----
    if (mt < 11) {
#pragma unroll
      for (int dt = 0; dt < 4; ++dt) {
        const int d = dt * 16 + l15;
#pragma unroll
        for (int r = 0; r < 4; ++r)
          st2s(sm, OFF_V, 128, mt * 16 + l4 * 4 + r, d, f2bf(o2[dt][r]));
      }
    }
    for (int idx = tid; idx < 2048; idx += 768) {
      const int j = idx >> 3;          // 0..255
      const int c8 = idx & 7;
      const float* src = proj_w + j * 256 + h * 64 + c8 * 8;
      float4 f0 = *(const float4*)(src);
      float4 f1 = *(const float4*)(src + 4);
      *(bf16x8*)(sm + OFF_Q + j * 128 + ((c8 * 16) ^ ((j & 7) << 4))) = cvt8(f0, f1);
    }
    __syncthreads();

    // ---- proj partial MFMA: out (+)= act @ Wproj^T (K=64), fp32 RMW ----
    if (mt < 11) {
      const int arow = mt * 16 + l15;
      bf16x8 af0 = ld8s(sm, OFF_V, 128, arow, l4 * 16);
      bf16x8 af1 = ld8s(sm, OFF_V, 128, arow, 64 + l4 * 16);
#pragma unroll
      for (int nt = 0; nt < 16; ++nt) {
        const int brow = nt * 16 + l15;
        bf16x8 bf0 = ld8s(sm, OFF_Q, 128, brow, l4 * 16);
        bf16x8 bf1 = ld8s(sm, OFF_Q, 128, brow, 64 + l4 * 16);
        f32x4 c = z;
        c = mfma16(af0, bf0, c);
        c = mfma16(af1, bf1, c);
        const int col = nt * 16 + l15;
#pragma unroll
        for (int r = 0; r < 4; ++r) {
          const int n = mt * 16 + l4 * 4 + r;
          if (n < 169) {
            float* p = out + ((size_t)b * 169 + n) * 256 + col;
            if (h == 0)      *p = c[r] + proj_b[col];
            else if (h == 3) __builtin_nontemporal_store(*p + c[r], p);
            else             *p += c[r];
          }
        }
      }
    }
    // next head's loop-top barrier protects Q/K/V regions
  }
}

extern "C" void kernel_launch(void* const* d_in, const int* in_sizes, int n_in,
                              void* d_out, int out_size, void* d_ws, size_t ws_size,
                              hipStream_t stream) {
  const float* x      = (const float*)d_in[0];
  const float* qkv_w  = (const float*)d_in[1];
  const float* proj_w = (const float*)d_in[2];
  const float* proj_b = (const float*)d_in[3];
  const float* dwc_w  = (const float*)d_in[4];
  const float* dwc_b  = (const float*)d_in[5];
  const float* an     = (const float*)d_in[6];
  const float* na     = (const float*)d_in[7];
  const float* ah     = (const float*)d_in[8];
  const float* aw     = (const float*)d_in[9];
  const float* ha     = (const float*)d_in[10];
  const float* wa     = (const float*)d_in[11];

  attn_kernel<<<1024, 768, 0, stream>>>(
      x, qkv_w, proj_w, proj_b, dwc_w, dwc_b,
      an, ah, aw, na, ha, wa, (float*)d_out);
}